// Round 2
// baseline (4163.973 us; speedup 1.0000x reference)
//
#include <hip/hip_runtime.h>

#define EPS_BN 1e-5f

// ---------------- workspace layout (float-unit offsets) ----------------
#define O_SRCD   0u
#define O_DSTD   17024u
#define O_COUNTS 34048u
#define O_OFFS   35072u
#define O_CURS   36096u
#define O_EIDX   37120u                    // now holds esrc (src node id, CSR-ordered)
#define O_PW1    54144u                    // [32][640]  (Wl1T|Wr1T|WpT)
#define O_PW2    74624u                    // [256][256] (Wl2T|Wr2T)
#define O_LW     140160u                   // PLW: [2][16w][8q][4dk][64lane][4gate]
#define O_BCOMB  402304u                   // [2][128j][4]
#define O_ABF    403328u                   // A1(256)|B1(256)|A2(128)|B2(128)
#define O_HWT    404352u                   // Ws1T(832)|Ws2T(2048)|Wh1T(10240)
#define O_BIG0   417536u                   // XL1  | later XL2,XR2
#define O_BIG1   (O_BIG0 + 16384000u)      // XR1  | later LO
#define O_BIG2   (O_BIG1 + 16384000u)      // H1
#define O_BIG3   (O_BIG2 + 16384000u)      // XP
#define O_BIG4   (O_BIG3 + 8192000u)       // Hres

__device__ __forceinline__ float rsum32(float p) {
  p += __shfl_xor(p, 1);  p += __shfl_xor(p, 2);  p += __shfl_xor(p, 4);
  p += __shfl_xor(p, 8);  p += __shfl_xor(p, 16); return p;
}
__device__ __forceinline__ float rsum64(float p) {
  p = rsum32(p); p += __shfl_xor(p, 32); return p;
}
__device__ __forceinline__ float lrelu(float x) { return x > 0.f ? x : 0.2f * x; }
__device__ __forceinline__ float eluf(float x)  { return x > 0.f ? x : expm1f(x); }
__device__ __forceinline__ float geluf(float x) { return 0.5f * x * (1.f + erff(x * 0.70710678118654752f)); }

// ---------------- prep kernels ----------------
__global__ void prep_edges(const int* __restrict__ ei, int* __restrict__ srcD,
                           int* __restrict__ dstD, int* __restrict__ counts) {
  int i = blockIdx.x * 256 + threadIdx.x;
  if (i < 1024) counts[i] = 0;
  if (i < 17000) {
    int s = (i < 16000) ? ei[i] : (i - 16000);
    int d = (i < 16000) ? ei[16000 + i] : (i - 16000);
    srcD[i] = s; dstD[i] = d;
  }
}
__global__ void hist_kernel(const int* __restrict__ dstD, int* __restrict__ counts) {
  int i = blockIdx.x * 256 + threadIdx.x;
  if (i < 17000) atomicAdd(&counts[dstD[i]], 1);
}
__global__ void scan_kernel(const int* __restrict__ counts, int* __restrict__ offs,
                            int* __restrict__ curs) {
  __shared__ int sh[1024];
  int i = threadIdx.x;
  int v = (i < 1000) ? counts[i] : 0;
  sh[i] = v;
  __syncthreads();
  for (int d = 1; d < 1024; d <<= 1) {
    int t = (i >= d) ? sh[i - d] : 0;
    __syncthreads();
    sh[i] += t;
    __syncthreads();
  }
  if (i < 1000) { offs[i + 1] = sh[i]; curs[i] = sh[i] - v; }
  if (i == 0) offs[0] = 0;
}
__global__ void fill_kernel(const int* __restrict__ srcD, const int* __restrict__ dstD,
                            int* __restrict__ curs, int* __restrict__ esrc) {
  int i = blockIdx.x * 256 + threadIdx.x;
  if (i < 17000) { int p = atomicAdd(&curs[dstD[i]], 1); esrc[p] = srcD[i]; }
}

__global__ void pack_kernel(
    const float* __restrict__ Wl1, const float* __restrict__ Wr1, const float* __restrict__ Wp,
    const float* __restrict__ Wl2, const float* __restrict__ Wr2,
    const float* __restrict__ Wih0, const float* __restrict__ Whh0,
    const float* __restrict__ bih0, const float* __restrict__ bhh0,
    const float* __restrict__ Wih1, const float* __restrict__ Whh1,
    const float* __restrict__ bih1, const float* __restrict__ bhh1,
    const float* __restrict__ g1, const float* __restrict__ be1, const float* __restrict__ m1,
    const float* __restrict__ v1, const float* __restrict__ bg1,
    const float* __restrict__ g2, const float* __restrict__ be2, const float* __restrict__ m2,
    const float* __restrict__ v2, const float* __restrict__ bg2,
    const float* __restrict__ Ws1, const float* __restrict__ Ws2, const float* __restrict__ Wh1,
    float* __restrict__ PW1, float* __restrict__ PW2, float* __restrict__ PLW,
    float* __restrict__ BC, float* __restrict__ ABF, float* __restrict__ HWT)
{
  int i = blockIdx.x * 256 + threadIdx.x;
  if (i < 262144) {  // LSTM packed weights: [L][w16][q8][dk4][lane64][gate4]
    int gate = i & 3, lane = (i >> 2) & 63, dk = (i >> 8) & 3,
        q = (i >> 10) & 7, w = (i >> 13) & 15, L = (i >> 17) & 1;
    int jlo = lane & 7, pp = lane >> 3;
    int mat = pp >> 2, kq = pp & 3;
    int jj = (w << 3) + jlo;
    int kk = (kq << 5) + (q << 2) + dk;
    const float* Wih = L ? Wih1 : Wih0;
    const float* Whh = L ? Whh1 : Whh0;
    PLW[i] = mat ? Whh[(gate * 128 + jj) * 128 + kk]
                 : Wih[(gate * 128 + jj) * 128 + kk];
  }
  if (i < 65536) { int c = i & 255, k = i >> 8;
    PW2[i] = (c < 128) ? Wl2[c * 256 + k] : Wr2[(c - 128) * 256 + k]; }
  if (i < 20480) { int g = i % 640, k = i / 640;
    PW1[i] = (g < 256) ? Wl1[g * 32 + k] : (g < 512) ? Wr1[(g - 256) * 32 + k]
                                                     : Wp[(g - 512) * 32 + k]; }
  if (i < 1024) { int u = i & 3, jj = (i >> 2) & 127, L = i >> 9;
    BC[i] = (L ? bih1 : bih0)[u * 128 + jj] + (L ? bhh1 : bhh0)[u * 128 + jj]; }
  if (i < 768) {
    if (i < 256) ABF[i] = g1[i] * rsqrtf(v1[i] + EPS_BN);
    else if (i < 512) { int c = i - 256; float a = g1[c] * rsqrtf(v1[c] + EPS_BN);
      ABF[i] = (bg1[c] - m1[c]) * a + be1[c]; }
    else if (i < 640) { int c = i - 512; ABF[i] = g2[c] * rsqrtf(v2[c] + EPS_BN); }
    else { int c = i - 640; float a = g2[c] * rsqrtf(v2[c] + EPS_BN);
      ABF[i] = (bg2[c] - m2[c]) * a + be2[c]; }
  }
  if (i < 13120) {
    if (i < 832) { int l = i & 63, c = i >> 6; HWT[i] = Ws1[l * 13 + c]; }
    else if (i < 2880) { int k = i - 832; int l = k & 31, jj = k >> 5; HWT[i] = Ws2[l * 64 + jj]; }
    else { int k = i - 2880; int l = k & 63, r = k >> 6; HWT[i] = Wh1[l * 160 + r]; }
  }
}

// ---------------- projection 1: x -> xl1(256) | xr1(256) | xp(128) ----------------
__global__ __launch_bounds__(320)
void proj1_kernel(const float* __restrict__ X, const float* __restrict__ PW1,
                  const float* __restrict__ bp,
                  float* __restrict__ XL1, float* __restrict__ XR1, float* __restrict__ XP)
{
  __shared__ __align__(16) float xs[32][16];
  const int tid = threadIdx.x;
  const int r0 = blockIdx.x * 16;
  for (int el = tid; el < 512; el += 320) {
    int r = el >> 5, k = el & 31;
    xs[k][r] = X[(size_t)(r0 + r) * 32 + k];
  }
  __syncthreads();
  const int gA = tid, gB = tid + 320;
  float accA[16], accB[16];
  const float iB = (gB >= 512) ? bp[gB - 512] : 0.f;
  #pragma unroll
  for (int r = 0; r < 16; ++r) { accA[r] = 0.f; accB[r] = iB; }
  for (int k = 0; k < 32; ++k) {
    float wA = PW1[k * 640 + gA], wB = PW1[k * 640 + gB];
    float xv[16];
    #pragma unroll
    for (int q = 0; q < 4; ++q)
      *reinterpret_cast<float4*>(&xv[q * 4]) = *reinterpret_cast<const float4*>(&xs[k][q * 4]);
    #pragma unroll
    for (int r = 0; r < 16; ++r) {
      accA[r] = fmaf(wA, xv[r], accA[r]);
      accB[r] = fmaf(wB, xv[r], accB[r]);
    }
  }
  for (int r = 0; r < 16; ++r) {
    size_t row = r0 + r;
    if (gA < 256) XL1[row * 256 + gA] = accA[r];
    else          XR1[row * 256 + (gA - 256)] = accA[r];
    if (gB < 512) XR1[row * 256 + (gB - 256)] = accB[r];
    else          XP[row * 128 + (gB - 512)] = accB[r];
  }
}

// ---------------- GAT layer 1 fused (2 heads, d=128) ----------------
__global__ __launch_bounds__(256)
void gat1_kernel(const float* __restrict__ XL, const float* __restrict__ XR,
                 const int* __restrict__ esrc,
                 const int* __restrict__ offs, const float* __restrict__ a1,
                 const float* __restrict__ ABF, float* __restrict__ H1)
{
  const int lane = threadIdx.x & 63;
  const int wv = threadIdx.x >> 6;
  const int n = blockIdx.x * 4 + wv;
  const int b = blockIdx.y;
  const int half = lane >> 5;
  __shared__ float lsh[4][128];
  const int beg = offs[n];
  const int deg = offs[n + 1] - beg;
  const float4 a4 = reinterpret_cast<const float4*>(a1)[lane];
  const float4* XLb = reinterpret_cast<const float4*>(XL) + (size_t)b * 64000;
  const float4 xr4 = reinterpret_cast<const float4*>(XR + (size_t)(b * 1000 + n) * 256)[lane];
  float m = -INFINITY, ssum = 0.f;
  {
    int sC = esrc[beg];
    float4 xc = XLb[(size_t)sC * 64 + lane];
    for (int i = 0; i < deg; ++i) {
      int nx = (i + 1 < deg) ? (i + 1) : i;
      int sN = esrc[beg + nx];
      float4 xn = XLb[(size_t)sN * 64 + lane];
      float p = lrelu(xc.x + xr4.x) * a4.x + lrelu(xc.y + xr4.y) * a4.y
              + lrelu(xc.z + xr4.z) * a4.z + lrelu(xc.w + xr4.w) * a4.w;
      p = rsum32(p);
      if (i < 64 && (lane & 31) == 0) lsh[wv][2 * i + half] = p;
      float mn = fmaxf(m, p);
      ssum = ssum * __expf(m - mn) + __expf(p - mn);
      m = mn;
      xc = xn;
    }
  }
  const float inv = 1.f / ssum;
  __builtin_amdgcn_wave_barrier();
  float4 acc = make_float4(0.f, 0.f, 0.f, 0.f);
  {
    int sC = esrc[beg];
    float4 xc = XLb[(size_t)sC * 64 + lane];
    for (int i = 0; i < deg; ++i) {
      int nx = (i + 1 < deg) ? (i + 1) : i;
      int sN = esrc[beg + nx];
      float4 xn = XLb[(size_t)sN * 64 + lane];
      float lg;
      if (i < 64) lg = lsh[wv][2 * i + half];
      else {
        float p = lrelu(xc.x + xr4.x) * a4.x + lrelu(xc.y + xr4.y) * a4.y
                + lrelu(xc.z + xr4.z) * a4.z + lrelu(xc.w + xr4.w) * a4.w;
        lg = rsum32(p);
      }
      const float al = __expf(lg - m) * inv;
      acc.x = fmaf(al, xc.x, acc.x);
      acc.y = fmaf(al, xc.y, acc.y);
      acc.z = fmaf(al, xc.z, acc.z);
      acc.w = fmaf(al, xc.w, acc.w);
      xc = xn;
    }
  }
  const float4 A4 = reinterpret_cast<const float4*>(ABF)[lane];
  const float4 B4 = reinterpret_cast<const float4*>(ABF + 256)[lane];
  float4 o;
  o.x = eluf(fmaf(acc.x, A4.x, B4.x));
  o.y = eluf(fmaf(acc.y, A4.y, B4.y));
  o.z = eluf(fmaf(acc.z, A4.z, B4.z));
  o.w = eluf(fmaf(acc.w, A4.w, B4.w));
  reinterpret_cast<float4*>(H1 + (size_t)(b * 1000 + n) * 256)[lane] = o;
}

// ---------------- projection 2: h1(256) -> xl2(128)|xr2(128) ----------------
__global__ __launch_bounds__(256)
void proj2_kernel(const float* __restrict__ H1, const float* __restrict__ PW2,
                  float* __restrict__ XL2, float* __restrict__ XR2)
{
  __shared__ __align__(16) float xs[256][20];
  const int tid = threadIdx.x;
  const int r0 = blockIdx.x * 16;
  for (int el = tid; el < 4096; el += 256) {
    int k = el & 255, r = el >> 8;
    xs[k][r] = H1[(size_t)(r0 + r) * 256 + k];
  }
  __syncthreads();
  float acc[16];
  #pragma unroll
  for (int r = 0; r < 16; ++r) acc[r] = 0.f;
  for (int k = 0; k < 256; ++k) {
    float wgt = PW2[k * 256 + tid];
    float xv[16];
    #pragma unroll
    for (int q = 0; q < 4; ++q)
      *reinterpret_cast<float4*>(&xv[q * 4]) = *reinterpret_cast<const float4*>(&xs[k][q * 4]);
    #pragma unroll
    for (int r = 0; r < 16; ++r) acc[r] = fmaf(wgt, xv[r], acc[r]);
  }
  float* dst = (tid < 128) ? XL2 : XR2;
  const int col = tid & 127;
  for (int r = 0; r < 16; ++r)
    dst[(size_t)(r0 + r) * 128 + col] = acc[r];
}

// ---------------- GAT layer 2 fused (1 head) + BN/ELU + residual ----------------
__global__ __launch_bounds__(256)
void gat2_kernel(const float* __restrict__ XL, const float* __restrict__ XR,
                 const int* __restrict__ esrc,
                 const int* __restrict__ offs, const float* __restrict__ a2,
                 const float* __restrict__ ABF, const float* __restrict__ XP,
                 float* __restrict__ Hout)
{
  const int lane = threadIdx.x & 63;
  const int wv = threadIdx.x >> 6;
  const int n = blockIdx.x * 4 + wv;
  const int b = blockIdx.y;
  __shared__ float lsh[4][96];
  const int beg = offs[n];
  const int deg = offs[n + 1] - beg;
  const float2 av = reinterpret_cast<const float2*>(a2)[lane];
  const float2* XLb = reinterpret_cast<const float2*>(XL) + (size_t)b * 64000;
  const float2 xr2 = reinterpret_cast<const float2*>(XR + (size_t)(b * 1000 + n) * 128)[lane];
  float m = -INFINITY, ssum = 0.f;
  {
    int sC = esrc[beg];
    float2 xc = XLb[(size_t)sC * 64 + lane];
    for (int i = 0; i < deg; ++i) {
      int nx = (i + 1 < deg) ? (i + 1) : i;
      int sN = esrc[beg + nx];
      float2 xn = XLb[(size_t)sN * 64 + lane];
      float p = lrelu(xc.x + xr2.x) * av.x + lrelu(xc.y + xr2.y) * av.y;
      p = rsum64(p);
      if (i < 96 && lane == 0) lsh[wv][i] = p;
      float mn = fmaxf(m, p);
      ssum = ssum * __expf(m - mn) + __expf(p - mn);
      m = mn;
      xc = xn;
    }
  }
  const float inv = 1.f / ssum;
  __builtin_amdgcn_wave_barrier();
  float2 acc = make_float2(0.f, 0.f);
  {
    int sC = esrc[beg];
    float2 xc = XLb[(size_t)sC * 64 + lane];
    for (int i = 0; i < deg; ++i) {
      int nx = (i + 1 < deg) ? (i + 1) : i;
      int sN = esrc[beg + nx];
      float2 xn = XLb[(size_t)sN * 64 + lane];
      float lg;
      if (i < 96) lg = lsh[wv][i];
      else {
        float p = lrelu(xc.x + xr2.x) * av.x + lrelu(xc.y + xr2.y) * av.y;
        lg = rsum64(p);
      }
      const float al = __expf(lg - m) * inv;
      acc.x = fmaf(al, xc.x, acc.x);
      acc.y = fmaf(al, xc.y, acc.y);
      xc = xn;
    }
  }
  const float2 A2 = reinterpret_cast<const float2*>(ABF + 512)[lane];
  const float2 B2 = reinterpret_cast<const float2*>(ABF + 640)[lane];
  const float2 xp = reinterpret_cast<const float2*>(XP + (size_t)(b * 1000 + n) * 128)[lane];
  float2 o;
  o.x = eluf(fmaf(acc.x, A2.x, B2.x)) + xp.x;
  o.y = eluf(fmaf(acc.y, A2.y, B2.y)) + xp.y;
  reinterpret_cast<float2*>(Hout + (size_t)(b * 1000 + n) * 128)[lane] = o;
}

// ---------------- fused 2-layer LSTM (8-way k-split, butterfly reduce) ----------------
#define FMA4(A, W, S) { (A).x = fmaf((W).x, (S), (A).x); (A).y = fmaf((W).y, (S), (A).y); \
                        (A).z = fmaf((W).z, (S), (A).z); (A).w = fmaf((W).w, (S), (A).w); }
#define AD4(a, b) { (a).x += (b).x; (a).y += (b).y; (a).z += (b).z; (a).w += (b).w; }
#define LROW 140

__device__ __forceinline__ float4 shflx4(float4 v, int msk) {
  float4 r;
  r.x = __shfl_xor(v.x, msk); r.y = __shfl_xor(v.y, msk);
  r.z = __shfl_xor(v.z, msk); r.w = __shfl_xor(v.w, msk);
  return r;
}

__device__ __forceinline__ void gates8(const float4* __restrict__ wb,
                                       const float* XA, const float* XB,
                                       int xoff, bool hi, float4 (&g)[16])
{
  const float* XS = hi ? XB : XA;
  #pragma unroll 2
  for (int q = 0; q < 8; ++q) {
    const float4* wq = wb + q * 256;
    float4 w0 = wq[0], w1 = wq[64], w2 = wq[128], w3 = wq[192];
    const float* xp = XS + xoff + (q << 2);
    #pragma unroll
    for (int s = 0; s < 16; ++s) {
      float4 xv = *reinterpret_cast<const float4*>(xp + s * LROW);
      FMA4(g[s], w0, xv.x);
      FMA4(g[s], w1, xv.y);
      FMA4(g[s], w2, xv.z);
      FMA4(g[s], w3, xv.w);
    }
  }
}

// narrowing 3-round butterfly over p = lane>>3; result: seqs 2p, 2p+1
__device__ __forceinline__ void reduce8(float4 (&g)[16], int lane, float4& ga, float4& gb)
{
  const bool b4 = (lane & 32) != 0, b2 = (lane & 16) != 0, b1 = (lane & 8) != 0;
  float4 t[8];
  #pragma unroll
  for (int i = 0; i < 8; ++i) {
    float4 keep = b4 ? g[8 + i] : g[i];
    float4 send = b4 ? g[i] : g[8 + i];
    float4 r = shflx4(send, 32);
    AD4(keep, r); t[i] = keep;
  }
  float4 u[4];
  #pragma unroll
  for (int i = 0; i < 4; ++i) {
    float4 keep = b2 ? t[4 + i] : t[i];
    float4 send = b2 ? t[i] : t[4 + i];
    float4 r = shflx4(send, 16);
    AD4(keep, r); u[i] = keep;
  }
  {
    float4 keep = b1 ? u[2] : u[0];
    float4 send = b1 ? u[0] : u[2];
    float4 r = shflx4(send, 8);
    AD4(keep, r); ga = keep;
  }
  {
    float4 keep = b1 ? u[3] : u[1];
    float4 send = b1 ? u[1] : u[3];
    float4 r = shflx4(send, 8);
    AD4(keep, r); gb = keep;
  }
}

__device__ __forceinline__ float cellf(float4 g, float& c) {
  const float ig = 1.f / (1.f + __expf(-g.x));
  const float fg = 1.f / (1.f + __expf(-g.y));
  const float gg = tanhf(g.z);
  const float og = 1.f / (1.f + __expf(-g.w));
  c = fmaf(fg, c, ig * gg);
  return og * tanhf(c);
}

__global__ __launch_bounds__(1024)
void lstm_kernel(const float* __restrict__ Hin, const float* __restrict__ PLW,
                 const float* __restrict__ BC, float* __restrict__ LO)
{
  __shared__ __align__(16) float xb[2][16][LROW];
  __shared__ __align__(16) float h1s[16][LROW];
  __shared__ __align__(16) float h2b[2][16][LROW];
  const int tid = threadIdx.x;
  const int lane = tid & 63;
  const int w = tid >> 6;                 // 0..15 (wave id; 8 hidden units per wave)
  const int jlo = lane & 7;
  const int p = lane >> 3;                // 0..7: (k,mat) slice; mat = p>>2
  const int j = (w << 3) + jlo;           // hidden unit 0..127
  const int xoff = 36 * (p & 3);          // skewed column base for this k-chunk
  const bool hi = p >= 4;                 // hh side
  const int jo = j + ((j >> 5) << 2);     // skewed LDS column for unit j
  const int q0 = blockIdx.x << 4;
  const int s0 = 2 * p;                   // owned seqs after reduce
  for (int i = tid; i < 16 * LROW; i += 1024) {
    (&h1s[0][0])[i] = 0.f;
    (&h2b[0][0][0])[i] = 0.f;
  }
  #pragma unroll
  for (int c = 0; c < 2; ++c) {
    int el = (c << 10) + tid;
    int s = el >> 7, k = el & 127;
    xb[0][s][k + ((k >> 5) << 2)] = Hin[((size_t)(((q0 + s) << 4))) * 128 + k];
  }
  const float4 b1 = *reinterpret_cast<const float4*>(BC + (j << 2));
  const float4 b2 = *reinterpret_cast<const float4*>(BC + 512 + (j << 2));
  const float4* PLW4 = reinterpret_cast<const float4*>(PLW);
  const float4* wb1 = PLW4 + (w << 11) + lane;
  const float4* wb2 = wb1 + 32768;
  float c1a = 0.f, c1b = 0.f, c2a = 0.f, c2b = 0.f;
  __syncthreads();
  int cur = 0;
  for (int t = 0; t < 16; ++t) {
    if (t < 15) {
      #pragma unroll
      for (int c = 0; c < 2; ++c) {
        int el = (c << 10) + tid;
        int s = el >> 7, k = el & 127;
        xb[cur ^ 1][s][k + ((k >> 5) << 2)] =
            Hin[((size_t)(((q0 + s) << 4) + (t + 1))) * 128 + k];
      }
    }
    float4 g[16];
    #pragma unroll
    for (int s = 0; s < 16; ++s) g[s] = make_float4(0.f, 0.f, 0.f, 0.f);
    gates8(wb1, &xb[cur][0][0], &h1s[0][0], xoff, hi, g);
    float4 ga, gb;
    reduce8(g, lane, ga, gb);
    AD4(ga, b1); AD4(gb, b1);
    float h1a = cellf(ga, c1a), h1b = cellf(gb, c1b);
    __syncthreads();                       // (A) all gates-1 reads done
    h1s[s0][jo] = h1a;
    h1s[s0 + 1][jo] = h1b;
    __syncthreads();                       // (B) h1 visible
    #pragma unroll
    for (int s = 0; s < 16; ++s) g[s] = make_float4(0.f, 0.f, 0.f, 0.f);
    gates8(wb2, &h1s[0][0], &h2b[cur][0][0], xoff, hi, g);
    reduce8(g, lane, ga, gb);
    AD4(ga, b2); AD4(gb, b2);
    float h2x = cellf(ga, c2a), h2y = cellf(gb, c2b);
    h2b[cur ^ 1][s0][jo] = h2x;
    h2b[cur ^ 1][s0 + 1][jo] = h2y;
    LO[((size_t)(((q0 + s0) << 4) + t)) * 128 + j] = h2x;
    LO[((size_t)(((q0 + s0 + 1) << 4) + t)) * 128 + j] = h2y;
    cur ^= 1;
  }
}

// ---------------- attention pool + skip MLP + head ----------------
__global__ __launch_bounds__(64)
void attn_kernel(const float* __restrict__ LO, const float* __restrict__ X,
                 const float* __restrict__ Wa, const float* __restrict__ ba,
                 const float* __restrict__ bs1, const float* __restrict__ bs2,
                 const float* __restrict__ bh1, const float* __restrict__ bh2,
                 const float* __restrict__ Wh2, const float* __restrict__ HWT,
                 float* __restrict__ out)
{
  const int q = blockIdx.x, l = threadIdx.x;
  const float* lob = LO + (size_t)q * 2048;
  float loa[16], lobv[16];
  #pragma unroll
  for (int t = 0; t < 16; ++t) {
    loa[t]  = lob[t * 128 + l];
    lobv[t] = lob[t * 128 + 64 + l];
  }
  const float wa = Wa[l], wb = Wa[64 + l];
  float sc[16];
  #pragma unroll
  for (int t = 0; t < 16; ++t) sc[t] = rsum64(loa[t] * wa + lobv[t] * wb) + ba[0];
  float mx = sc[0];
  #pragma unroll
  for (int t = 1; t < 16; ++t) mx = fmaxf(mx, sc[t]);
  float den = 0.f;
  #pragma unroll
  for (int t = 0; t < 16; ++t) { sc[t] = __expf(sc[t] - mx); den += sc[t]; }
  const float inv = 1.f / den;
  float ca = 0.f, cb = 0.f;
  #pragma unroll
  for (int t = 0; t < 16; ++t) {
    float wgt = sc[t] * inv;
    ca = fmaf(wgt, loa[t], ca);
    cb = fmaf(wgt, lobv[t], cb);
  }
  __shared__ float zsh[160];
  __shared__ float hsk[64];
  __shared__ float skin[16];
  zsh[l] = ca; zsh[64 + l] = cb;
  const int bb = q / 1000, nn = q - bb * 1000;
  if (l < 13) skin[l] = X[(size_t)((bb * 16 + 15) * 1000 + nn) * 32 + l];
  __syncthreads();
  float h1 = bs1[l];
  for (int c = 0; c < 13; ++c) h1 = fmaf(skin[c], HWT[c * 64 + l], h1);
  h1 = geluf(h1);
  hsk[l] = h1;
  __syncthreads();
  if (l < 32) {
    float a = bs2[l];
    for (int jj = 0; jj < 64; ++jj) a = fmaf(hsk[jj], HWT[832 + jj * 32 + l], a);
    zsh[128 + l] = a;
  }
  __syncthreads();
  float hh = bh1[l];
  for (int r = 0; r < 160; ++r) hh = fmaf(zsh[r], HWT[2880 + r * 64 + l], hh);
  hh = geluf(hh);
  float s = rsum64(hh * Wh2[l]);
  if (l == 0) out[q] = s + bh2[0];
}

// ---------------- launch ----------------
extern "C" void kernel_launch(void* const* d_in, const int* in_sizes, int n_in,
                              void* d_out, int out_size, void* d_ws, size_t ws_size,
                              hipStream_t stream)
{
  const float* x    = (const float*)d_in[0];
  const int*   ei   = (const int*)d_in[1];
  const float* Wp   = (const float*)d_in[2];
  const float* bp   = (const float*)d_in[3];
  const float* Wl1  = (const float*)d_in[4];
  const float* Wr1  = (const float*)d_in[5];
  const float* a1   = (const float*)d_in[6];
  const float* bg1  = (const float*)d_in[7];
  const float* g1   = (const float*)d_in[8];
  const float* be1  = (const float*)d_in[9];
  const float* m1   = (const float*)d_in[10];
  const float* v1   = (const float*)d_in[11];
  const float* Wl2  = (const float*)d_in[12];
  const float* Wr2  = (const float*)d_in[13];
  const float* a2   = (const float*)d_in[14];
  const float* bg2  = (const float*)d_in[15];
  const float* g2   = (const float*)d_in[16];
  const float* be2  = (const float*)d_in[17];
  const float* m2   = (const float*)d_in[18];
  const float* v2   = (const float*)d_in[19];
  const float* Wih0 = (const float*)d_in[20];
  const float* Whh0 = (const float*)d_in[21];
  const float* bih0 = (const float*)d_in[22];
  const float* bhh0 = (const float*)d_in[23];
  const float* Wih1 = (const float*)d_in[24];
  const float* Whh1 = (const float*)d_in[25];
  const float* bih1 = (const float*)d_in[26];
  const float* bhh1 = (const float*)d_in[27];
  const float* Wa   = (const float*)d_in[28];
  const float* ba   = (const float*)d_in[29];
  const float* Ws1  = (const float*)d_in[30];
  const float* bs1  = (const float*)d_in[31];
  const float* Ws2  = (const float*)d_in[32];
  const float* bs2  = (const float*)d_in[33];
  const float* Wh1  = (const float*)d_in[34];
  const float* bh1  = (const float*)d_in[35];
  const float* Wh2  = (const float*)d_in[36];
  const float* bh2  = (const float*)d_in[37];

  float* ws = (float*)d_ws;
  int* srcD   = (int*)(ws + O_SRCD);
  int* dstD   = (int*)(ws + O_DSTD);
  int* counts = (int*)(ws + O_COUNTS);
  int* offs   = (int*)(ws + O_OFFS);
  int* curs   = (int*)(ws + O_CURS);
  int* esrc   = (int*)(ws + O_EIDX);
  float* PW1  = ws + O_PW1;
  float* PW2  = ws + O_PW2;
  float* PLW  = ws + O_LW;
  float* BC   = ws + O_BCOMB;
  float* ABF  = ws + O_ABF;
  float* HWT  = ws + O_HWT;
  float* XL1  = ws + O_BIG0;
  float* XR1  = ws + O_BIG1;
  float* H1   = ws + O_BIG2;
  float* XP   = ws + O_BIG3;
  float* Hres = ws + O_BIG4;
  float* XL2  = ws + O_BIG0;             // reuse (XL1 dead)
  float* XR2  = ws + O_BIG0 + 8192000u;
  float* LOp  = ws + O_BIG1;             // reuse (XR1 dead)
  float* outp = (float*)d_out;

  prep_edges<<<67, 256, 0, stream>>>(ei, srcD, dstD, counts);
  hist_kernel<<<67, 256, 0, stream>>>(dstD, counts);
  scan_kernel<<<1, 1024, 0, stream>>>(counts, offs, curs);
  fill_kernel<<<67, 256, 0, stream>>>(srcD, dstD, curs, esrc);
  pack_kernel<<<1024, 256, 0, stream>>>(Wl1, Wr1, Wp, Wl2, Wr2,
      Wih0, Whh0, bih0, bhh0, Wih1, Whh1, bih1, bhh1,
      g1, be1, m1, v1, bg1, g2, be2, m2, v2, bg2,
      Ws1, Ws2, Wh1, PW1, PW2, PLW, BC, ABF, HWT);
  proj1_kernel<<<4000, 320, 0, stream>>>(x, PW1, bp, XL1, XR1, XP);
  gat1_kernel<<<dim3(250, 64), 256, 0, stream>>>(XL1, XR1, esrc, offs, a1, ABF, H1);
  proj2_kernel<<<4000, 256, 0, stream>>>(H1, PW2, XL2, XR2);
  gat2_kernel<<<dim3(250, 64), 256, 0, stream>>>(XL2, XR2, esrc, offs, a2, ABF, XP, Hres);
  lstm_kernel<<<250, 1024, 0, stream>>>(Hres, PLW, BC, LOp);
  attn_kernel<<<4000, 64, 0, stream>>>(LOp, x, Wa, ba, bs1, bs2, bh1, bh2, Wh2, HWT, outp);
}

// Round 3
// 1565.933 us; speedup vs baseline: 2.6591x; 2.6591x over previous
//
#include <hip/hip_runtime.h>

#define EPS_BN 1e-5f

// ---------------- workspace layout (float-unit offsets) ----------------
#define O_SRCD   0u
#define O_DSTD   17024u
#define O_COUNTS 34048u
#define O_OFFS   35072u
#define O_CURS   36096u
#define O_EIDX   37120u                    // esrc (src node id, CSR-ordered)
#define O_PW1    54144u                    // [32][640]  (Wl1T|Wr1T|WpT)
#define O_PW2    74624u                    // [256][256] (Wl2T|Wr2T)
#define O_LW     140160u                   // PLW: [2][16w][8q][4dk][64lane][4gate]
#define O_BCOMB  402304u                   // [2][128j][4]
#define O_ABF    403328u                   // A1(256)|B1(256)|A2(128)|B2(128)
#define O_HWT    404352u                   // Ws1T(832)|Ws2T(2048)|Wh1T(10240)
#define O_BIG0   417536u                   // XL1  | later XL2,XR2
#define O_BIG1   (O_BIG0 + 16384000u)      // XR1  | later LO
#define O_BIG2   (O_BIG1 + 16384000u)      // H1
#define O_BIG3   (O_BIG2 + 16384000u)      // XP
#define O_BIG4   (O_BIG3 + 8192000u)       // Hres

__device__ __forceinline__ float rsum32(float p) {
  p += __shfl_xor(p, 1);  p += __shfl_xor(p, 2);  p += __shfl_xor(p, 4);
  p += __shfl_xor(p, 8);  p += __shfl_xor(p, 16); return p;
}
__device__ __forceinline__ float rsum64(float p) {
  p = rsum32(p); p += __shfl_xor(p, 32); return p;
}
__device__ __forceinline__ float lrelu(float x) { return x > 0.f ? x : 0.2f * x; }
__device__ __forceinline__ float eluf(float x)  { return x > 0.f ? x : expm1f(x); }
__device__ __forceinline__ float geluf(float x) { return 0.5f * x * (1.f + erff(x * 0.70710678118654752f)); }

// ---------------- prep kernels ----------------
__global__ void prep_edges(const int* __restrict__ ei, int* __restrict__ srcD,
                           int* __restrict__ dstD, int* __restrict__ counts) {
  int i = blockIdx.x * 256 + threadIdx.x;
  if (i < 1024) counts[i] = 0;
  if (i < 17000) {
    int s = (i < 16000) ? ei[i] : (i - 16000);
    int d = (i < 16000) ? ei[16000 + i] : (i - 16000);
    srcD[i] = s; dstD[i] = d;
  }
}
__global__ void hist_kernel(const int* __restrict__ dstD, int* __restrict__ counts) {
  int i = blockIdx.x * 256 + threadIdx.x;
  if (i < 17000) atomicAdd(&counts[dstD[i]], 1);
}
__global__ void scan_kernel(const int* __restrict__ counts, int* __restrict__ offs,
                            int* __restrict__ curs) {
  __shared__ int sh[1024];
  int i = threadIdx.x;
  int v = (i < 1000) ? counts[i] : 0;
  sh[i] = v;
  __syncthreads();
  for (int d = 1; d < 1024; d <<= 1) {
    int t = (i >= d) ? sh[i - d] : 0;
    __syncthreads();
    sh[i] += t;
    __syncthreads();
  }
  if (i < 1000) { offs[i + 1] = sh[i]; curs[i] = sh[i] - v; }
  if (i == 0) offs[0] = 0;
}
__global__ void fill_kernel(const int* __restrict__ srcD, const int* __restrict__ dstD,
                            int* __restrict__ curs, int* __restrict__ esrc) {
  int i = blockIdx.x * 256 + threadIdx.x;
  if (i < 17000) { int p = atomicAdd(&curs[dstD[i]], 1); esrc[p] = srcD[i]; }
}

__global__ void pack_kernel(
    const float* __restrict__ Wl1, const float* __restrict__ Wr1, const float* __restrict__ Wp,
    const float* __restrict__ Wl2, const float* __restrict__ Wr2,
    const float* __restrict__ Wih0, const float* __restrict__ Whh0,
    const float* __restrict__ bih0, const float* __restrict__ bhh0,
    const float* __restrict__ Wih1, const float* __restrict__ Whh1,
    const float* __restrict__ bih1, const float* __restrict__ bhh1,
    const float* __restrict__ g1, const float* __restrict__ be1, const float* __restrict__ m1,
    const float* __restrict__ v1, const float* __restrict__ bg1,
    const float* __restrict__ g2, const float* __restrict__ be2, const float* __restrict__ m2,
    const float* __restrict__ v2, const float* __restrict__ bg2,
    const float* __restrict__ Ws1, const float* __restrict__ Ws2, const float* __restrict__ Wh1,
    float* __restrict__ PW1, float* __restrict__ PW2, float* __restrict__ PLW,
    float* __restrict__ BC, float* __restrict__ ABF, float* __restrict__ HWT)
{
  int i = blockIdx.x * 256 + threadIdx.x;
  if (i < 262144) {  // LSTM packed weights: [L][w16][q8][dk4][lane64][gate4]
    int gate = i & 3, lane = (i >> 2) & 63, dk = (i >> 8) & 3,
        q = (i >> 10) & 7, w = (i >> 13) & 15, L = (i >> 17) & 1;
    int jlo = lane & 7, pp = lane >> 3;
    int mat = pp >> 2, kq = pp & 3;
    int jj = (w << 3) + jlo;
    int kk = (kq << 5) + (q << 2) + dk;
    const float* Wih = L ? Wih1 : Wih0;
    const float* Whh = L ? Whh1 : Whh0;
    PLW[i] = mat ? Whh[(gate * 128 + jj) * 128 + kk]
                 : Wih[(gate * 128 + jj) * 128 + kk];
  }
  if (i < 65536) { int c = i & 255, k = i >> 8;
    PW2[i] = (c < 128) ? Wl2[c * 256 + k] : Wr2[(c - 128) * 256 + k]; }
  if (i < 20480) { int g = i % 640, k = i / 640;
    PW1[i] = (g < 256) ? Wl1[g * 32 + k] : (g < 512) ? Wr1[(g - 256) * 32 + k]
                                                     : Wp[(g - 512) * 32 + k]; }
  if (i < 1024) { int u = i & 3, jj = (i >> 2) & 127, L = i >> 9;
    BC[i] = (L ? bih1 : bih0)[u * 128 + jj] + (L ? bhh1 : bhh0)[u * 128 + jj]; }
  if (i < 768) {
    if (i < 256) ABF[i] = g1[i] * rsqrtf(v1[i] + EPS_BN);
    else if (i < 512) { int c = i - 256; float a = g1[c] * rsqrtf(v1[c] + EPS_BN);
      ABF[i] = (bg1[c] - m1[c]) * a + be1[c]; }
    else if (i < 640) { int c = i - 512; ABF[i] = g2[c] * rsqrtf(v2[c] + EPS_BN); }
    else { int c = i - 640; float a = g2[c] * rsqrtf(v2[c] + EPS_BN);
      ABF[i] = (bg2[c] - m2[c]) * a + be2[c]; }
  }
  if (i < 13120) {
    if (i < 832) { int l = i & 63, c = i >> 6; HWT[i] = Ws1[l * 13 + c]; }
    else if (i < 2880) { int k = i - 832; int l = k & 31, jj = k >> 5; HWT[i] = Ws2[l * 64 + jj]; }
    else { int k = i - 2880; int l = k & 63, r = k >> 6; HWT[i] = Wh1[l * 160 + r]; }
  }
}

// ---------------- projection 1: x -> xl1(256) | xr1(256) | xp(128) ----------------
__global__ __launch_bounds__(320)
void proj1_kernel(const float* __restrict__ X, const float* __restrict__ PW1,
                  const float* __restrict__ bp,
                  float* __restrict__ XL1, float* __restrict__ XR1, float* __restrict__ XP)
{
  __shared__ __align__(16) float xs[32][16];
  const int tid = threadIdx.x;
  const int r0 = blockIdx.x * 16;
  for (int el = tid; el < 512; el += 320) {
    int r = el >> 5, k = el & 31;
    xs[k][r] = X[(size_t)(r0 + r) * 32 + k];
  }
  __syncthreads();
  const int gA = tid, gB = tid + 320;
  float accA[16], accB[16];
  const float iB = (gB >= 512) ? bp[gB - 512] : 0.f;
  #pragma unroll
  for (int r = 0; r < 16; ++r) { accA[r] = 0.f; accB[r] = iB; }
  for (int k = 0; k < 32; ++k) {
    float wA = PW1[k * 640 + gA], wB = PW1[k * 640 + gB];
    float xv[16];
    #pragma unroll
    for (int q = 0; q < 4; ++q)
      *reinterpret_cast<float4*>(&xv[q * 4]) = *reinterpret_cast<const float4*>(&xs[k][q * 4]);
    #pragma unroll
    for (int r = 0; r < 16; ++r) {
      accA[r] = fmaf(wA, xv[r], accA[r]);
      accB[r] = fmaf(wB, xv[r], accB[r]);
    }
  }
  for (int r = 0; r < 16; ++r) {
    size_t row = r0 + r;
    if (gA < 256) XL1[row * 256 + gA] = accA[r];
    else          XR1[row * 256 + (gA - 256)] = accA[r];
    if (gB < 512) XR1[row * 256 + (gB - 256)] = accB[r];
    else          XP[row * 128 + (gB - 512)] = accB[r];
  }
}

// ---------------- GAT layer 1 fused (2 heads, d=128) ----------------
__global__ __launch_bounds__(256)
void gat1_kernel(const float* __restrict__ XL, const float* __restrict__ XR,
                 const int* __restrict__ esrc,
                 const int* __restrict__ offs, const float* __restrict__ a1,
                 const float* __restrict__ ABF, float* __restrict__ H1)
{
  const int lane = threadIdx.x & 63;
  const int wv = threadIdx.x >> 6;
  const int n = blockIdx.x * 4 + wv;
  const int b = blockIdx.y;
  const int half = lane >> 5;
  __shared__ float lsh[4][128];
  const int beg = offs[n];
  const int deg = offs[n + 1] - beg;
  const float4 a4 = reinterpret_cast<const float4*>(a1)[lane];
  const float4* XLb = reinterpret_cast<const float4*>(XL) + (size_t)b * 64000;
  const float4 xr4 = reinterpret_cast<const float4*>(XR + (size_t)(b * 1000 + n) * 256)[lane];
  float m = -INFINITY, ssum = 0.f;
  {
    int sC = esrc[beg];
    float4 xc = XLb[(size_t)sC * 64 + lane];
    for (int i = 0; i < deg; ++i) {
      int nx = (i + 1 < deg) ? (i + 1) : i;
      int sN = esrc[beg + nx];
      float4 xn = XLb[(size_t)sN * 64 + lane];
      float p = lrelu(xc.x + xr4.x) * a4.x + lrelu(xc.y + xr4.y) * a4.y
              + lrelu(xc.z + xr4.z) * a4.z + lrelu(xc.w + xr4.w) * a4.w;
      p = rsum32(p);
      if (i < 64 && (lane & 31) == 0) lsh[wv][2 * i + half] = p;
      float mn = fmaxf(m, p);
      ssum = ssum * __expf(m - mn) + __expf(p - mn);
      m = mn;
      xc = xn;
    }
  }
  const float inv = 1.f / ssum;
  __builtin_amdgcn_wave_barrier();
  float4 acc = make_float4(0.f, 0.f, 0.f, 0.f);
  {
    int sC = esrc[beg];
    float4 xc = XLb[(size_t)sC * 64 + lane];
    for (int i = 0; i < deg; ++i) {
      int nx = (i + 1 < deg) ? (i + 1) : i;
      int sN = esrc[beg + nx];
      float4 xn = XLb[(size_t)sN * 64 + lane];
      float lg;
      if (i < 64) lg = lsh[wv][2 * i + half];
      else {
        float p = lrelu(xc.x + xr4.x) * a4.x + lrelu(xc.y + xr4.y) * a4.y
                + lrelu(xc.z + xr4.z) * a4.z + lrelu(xc.w + xr4.w) * a4.w;
        lg = rsum32(p);
      }
      const float al = __expf(lg - m) * inv;
      acc.x = fmaf(al, xc.x, acc.x);
      acc.y = fmaf(al, xc.y, acc.y);
      acc.z = fmaf(al, xc.z, acc.z);
      acc.w = fmaf(al, xc.w, acc.w);
      xc = xn;
    }
  }
  const float4 A4 = reinterpret_cast<const float4*>(ABF)[lane];
  const float4 B4 = reinterpret_cast<const float4*>(ABF + 256)[lane];
  float4 o;
  o.x = eluf(fmaf(acc.x, A4.x, B4.x));
  o.y = eluf(fmaf(acc.y, A4.y, B4.y));
  o.z = eluf(fmaf(acc.z, A4.z, B4.z));
  o.w = eluf(fmaf(acc.w, A4.w, B4.w));
  reinterpret_cast<float4*>(H1 + (size_t)(b * 1000 + n) * 256)[lane] = o;
}

// ---------------- projection 2: h1(256) -> xl2(128)|xr2(128) ----------------
__global__ __launch_bounds__(256)
void proj2_kernel(const float* __restrict__ H1, const float* __restrict__ PW2,
                  float* __restrict__ XL2, float* __restrict__ XR2)
{
  __shared__ __align__(16) float xs[256][20];
  const int tid = threadIdx.x;
  const int r0 = blockIdx.x * 16;
  for (int el = tid; el < 4096; el += 256) {
    int k = el & 255, r = el >> 8;
    xs[k][r] = H1[(size_t)(r0 + r) * 256 + k];
  }
  __syncthreads();
  float acc[16];
  #pragma unroll
  for (int r = 0; r < 16; ++r) acc[r] = 0.f;
  for (int k = 0; k < 256; ++k) {
    float wgt = PW2[k * 256 + tid];
    float xv[16];
    #pragma unroll
    for (int q = 0; q < 4; ++q)
      *reinterpret_cast<float4*>(&xv[q * 4]) = *reinterpret_cast<const float4*>(&xs[k][q * 4]);
    #pragma unroll
    for (int r = 0; r < 16; ++r) acc[r] = fmaf(wgt, xv[r], acc[r]);
  }
  float* dst = (tid < 128) ? XL2 : XR2;
  const int col = tid & 127;
  for (int r = 0; r < 16; ++r)
    dst[(size_t)(r0 + r) * 128 + col] = acc[r];
}

// ---------------- GAT layer 2 fused (1 head) + BN/ELU + residual ----------------
__global__ __launch_bounds__(256)
void gat2_kernel(const float* __restrict__ XL, const float* __restrict__ XR,
                 const int* __restrict__ esrc,
                 const int* __restrict__ offs, const float* __restrict__ a2,
                 const float* __restrict__ ABF, const float* __restrict__ XP,
                 float* __restrict__ Hout)
{
  const int lane = threadIdx.x & 63;
  const int wv = threadIdx.x >> 6;
  const int n = blockIdx.x * 4 + wv;
  const int b = blockIdx.y;
  __shared__ float lsh[4][96];
  const int beg = offs[n];
  const int deg = offs[n + 1] - beg;
  const float2 av = reinterpret_cast<const float2*>(a2)[lane];
  const float2* XLb = reinterpret_cast<const float2*>(XL) + (size_t)b * 64000;
  const float2 xr2 = reinterpret_cast<const float2*>(XR + (size_t)(b * 1000 + n) * 128)[lane];
  float m = -INFINITY, ssum = 0.f;
  {
    int sC = esrc[beg];
    float2 xc = XLb[(size_t)sC * 64 + lane];
    for (int i = 0; i < deg; ++i) {
      int nx = (i + 1 < deg) ? (i + 1) : i;
      int sN = esrc[beg + nx];
      float2 xn = XLb[(size_t)sN * 64 + lane];
      float p = lrelu(xc.x + xr2.x) * av.x + lrelu(xc.y + xr2.y) * av.y;
      p = rsum64(p);
      if (i < 96 && lane == 0) lsh[wv][i] = p;
      float mn = fmaxf(m, p);
      ssum = ssum * __expf(m - mn) + __expf(p - mn);
      m = mn;
      xc = xn;
    }
  }
  const float inv = 1.f / ssum;
  __builtin_amdgcn_wave_barrier();
  float2 acc = make_float2(0.f, 0.f);
  {
    int sC = esrc[beg];
    float2 xc = XLb[(size_t)sC * 64 + lane];
    for (int i = 0; i < deg; ++i) {
      int nx = (i + 1 < deg) ? (i + 1) : i;
      int sN = esrc[beg + nx];
      float2 xn = XLb[(size_t)sN * 64 + lane];
      float lg;
      if (i < 96) lg = lsh[wv][i];
      else {
        float p = lrelu(xc.x + xr2.x) * av.x + lrelu(xc.y + xr2.y) * av.y;
        lg = rsum64(p);
      }
      const float al = __expf(lg - m) * inv;
      acc.x = fmaf(al, xc.x, acc.x);
      acc.y = fmaf(al, xc.y, acc.y);
      xc = xn;
    }
  }
  const float2 A2 = reinterpret_cast<const float2*>(ABF + 512)[lane];
  const float2 B2 = reinterpret_cast<const float2*>(ABF + 640)[lane];
  const float2 xp = reinterpret_cast<const float2*>(XP + (size_t)(b * 1000 + n) * 128)[lane];
  float2 o;
  o.x = eluf(fmaf(acc.x, A2.x, B2.x)) + xp.x;
  o.y = eluf(fmaf(acc.y, A2.y, B2.y)) + xp.y;
  reinterpret_cast<float2*>(Hout + (size_t)(b * 1000 + n) * 128)[lane] = o;
}

// ---------------- fused 2-layer LSTM (8-way k-split, butterfly reduce) ----------------
#define FMA4(A, W, S) { (A).x = fmaf((W).x, (S), (A).x); (A).y = fmaf((W).y, (S), (A).y); \
                        (A).z = fmaf((W).z, (S), (A).z); (A).w = fmaf((W).w, (S), (A).w); }
#define AD4(a, b) { (a).x += (b).x; (a).y += (b).y; (a).z += (b).z; (a).w += (b).w; }
#define LROW 140

__device__ __forceinline__ float4 shflx4(float4 v, int msk) {
  float4 r;
  r.x = __shfl_xor(v.x, msk); r.y = __shfl_xor(v.y, msk);
  r.z = __shfl_xor(v.z, msk); r.w = __shfl_xor(v.w, msk);
  return r;
}

// weights double-buffered 1 q-step ahead; acc g[16] float4 stays register-resident
__device__ __forceinline__ void gates8(const float4* __restrict__ wb,
                                       const float* XS, int xoff, float4 (&g)[16])
{
  float4 w0 = wb[0], w1 = wb[64], w2 = wb[128], w3 = wb[192];
  #pragma unroll
  for (int q = 0; q < 8; ++q) {
    float4 c0 = w0, c1 = w1, c2 = w2, c3 = w3;
    if (q < 7) {
      const float4* nq = wb + (q + 1) * 256;
      w0 = nq[0]; w1 = nq[64]; w2 = nq[128]; w3 = nq[192];
    }
    const float* xp = XS + xoff + (q << 2);
    #pragma unroll
    for (int s = 0; s < 16; ++s) {
      float4 xv = *reinterpret_cast<const float4*>(xp + s * LROW);
      FMA4(g[s], c0, xv.x);
      FMA4(g[s], c1, xv.y);
      FMA4(g[s], c2, xv.z);
      FMA4(g[s], c3, xv.w);
    }
  }
}

// narrowing 3-round butterfly over p = lane>>3; result: seqs 2p, 2p+1
__device__ __forceinline__ void reduce8(float4 (&g)[16], int lane, float4& ga, float4& gb)
{
  const bool b4 = (lane & 32) != 0, b2 = (lane & 16) != 0, b1 = (lane & 8) != 0;
  float4 t[8];
  #pragma unroll
  for (int i = 0; i < 8; ++i) {
    float4 keep = b4 ? g[8 + i] : g[i];
    float4 send = b4 ? g[i] : g[8 + i];
    float4 r = shflx4(send, 32);
    AD4(keep, r); t[i] = keep;
  }
  float4 u[4];
  #pragma unroll
  for (int i = 0; i < 4; ++i) {
    float4 keep = b2 ? t[4 + i] : t[i];
    float4 send = b2 ? t[i] : t[4 + i];
    float4 r = shflx4(send, 16);
    AD4(keep, r); u[i] = keep;
  }
  {
    float4 keep = b1 ? u[2] : u[0];
    float4 send = b1 ? u[0] : u[2];
    float4 r = shflx4(send, 8);
    AD4(keep, r); ga = keep;
  }
  {
    float4 keep = b1 ? u[3] : u[1];
    float4 send = b1 ? u[1] : u[3];
    float4 r = shflx4(send, 8);
    AD4(keep, r); gb = keep;
  }
}

__device__ __forceinline__ float cellf(float4 g, float& c) {
  const float ig = 1.f / (1.f + __expf(-g.x));
  const float fg = 1.f / (1.f + __expf(-g.y));
  const float gg = tanhf(g.z);
  const float og = 1.f / (1.f + __expf(-g.w));
  c = fmaf(fg, c, ig * gg);
  return og * tanhf(c);
}

// 1024 threads = 16 waves = 4 waves/EU -> VGPR cap 128 (g[16] needs 64; total ~116).
// Bare __launch_bounds__(1024) let the compiler pick 64 VGPR and spill 13 GB to scratch.
__global__ __launch_bounds__(1024, 4)
void lstm_kernel(const float* __restrict__ Hin, const float* __restrict__ PLW,
                 const float* __restrict__ BC, float* __restrict__ LO)
{
  __shared__ __align__(16) float xb[2][16][LROW];
  __shared__ __align__(16) float h1s[16][LROW];
  __shared__ __align__(16) float h2b[2][16][LROW];
  const int tid = threadIdx.x;
  const int lane = tid & 63;
  const int w = tid >> 6;                 // 0..15 (wave id; 8 hidden units per wave)
  const int jlo = lane & 7;
  const int p = lane >> 3;                // 0..7: (k,mat) slice; mat = p>>2
  const int j = (w << 3) + jlo;           // hidden unit 0..127
  const int xoff = 36 * (p & 3);          // skewed column base for this k-chunk
  const bool hi = p >= 4;                 // hh side
  const int jo = j + ((j >> 5) << 2);     // skewed LDS column for unit j
  const int q0 = blockIdx.x << 4;
  const int s0 = 2 * p;                   // owned seqs after reduce
  for (int i = tid; i < 16 * LROW; i += 1024) {
    (&h1s[0][0])[i] = 0.f;
    (&h2b[0][0][0])[i] = 0.f;
  }
  #pragma unroll
  for (int c = 0; c < 2; ++c) {
    int el = (c << 10) + tid;
    int s = el >> 7, k = el & 127;
    xb[0][s][k + ((k >> 5) << 2)] = Hin[((size_t)(((q0 + s) << 4))) * 128 + k];
  }
  const float4 b1 = *reinterpret_cast<const float4*>(BC + (j << 2));
  const float4 b2 = *reinterpret_cast<const float4*>(BC + 512 + (j << 2));
  const float4* PLW4 = reinterpret_cast<const float4*>(PLW);
  const float4* wb1 = PLW4 + (w << 11) + lane;
  const float4* wb2 = wb1 + 32768;
  float c1a = 0.f, c1b = 0.f, c2a = 0.f, c2b = 0.f;
  __syncthreads();
  int cur = 0;
  for (int t = 0; t < 16; ++t) {
    if (t < 15) {
      #pragma unroll
      for (int c = 0; c < 2; ++c) {
        int el = (c << 10) + tid;
        int s = el >> 7, k = el & 127;
        xb[cur ^ 1][s][k + ((k >> 5) << 2)] =
            Hin[((size_t)(((q0 + s) << 4) + (t + 1))) * 128 + k];
      }
    }
    float4 g[16];
    #pragma unroll
    for (int s = 0; s < 16; ++s) g[s] = make_float4(0.f, 0.f, 0.f, 0.f);
    gates8(wb1, hi ? &h1s[0][0] : &xb[cur][0][0], xoff, g);
    float4 ga, gb;
    reduce8(g, lane, ga, gb);
    AD4(ga, b1); AD4(gb, b1);
    float h1a = cellf(ga, c1a), h1b = cellf(gb, c1b);
    __syncthreads();                       // (A) all gates-1 reads done
    h1s[s0][jo] = h1a;
    h1s[s0 + 1][jo] = h1b;
    __syncthreads();                       // (B) h1 visible
    #pragma unroll
    for (int s = 0; s < 16; ++s) g[s] = make_float4(0.f, 0.f, 0.f, 0.f);
    gates8(wb2, hi ? &h2b[cur][0][0] : &h1s[0][0], xoff, g);
    reduce8(g, lane, ga, gb);
    AD4(ga, b2); AD4(gb, b2);
    float h2x = cellf(ga, c2a), h2y = cellf(gb, c2b);
    h2b[cur ^ 1][s0][jo] = h2x;
    h2b[cur ^ 1][s0 + 1][jo] = h2y;
    LO[((size_t)(((q0 + s0) << 4) + t)) * 128 + j] = h2x;
    LO[((size_t)(((q0 + s0 + 1) << 4) + t)) * 128 + j] = h2y;
    cur ^= 1;
  }
}

// ---------------- attention pool + skip MLP + head ----------------
__global__ __launch_bounds__(64)
void attn_kernel(const float* __restrict__ LO, const float* __restrict__ X,
                 const float* __restrict__ Wa, const float* __restrict__ ba,
                 const float* __restrict__ bs1, const float* __restrict__ bs2,
                 const float* __restrict__ bh1, const float* __restrict__ bh2,
                 const float* __restrict__ Wh2, const float* __restrict__ HWT,
                 float* __restrict__ out)
{
  const int q = blockIdx.x, l = threadIdx.x;
  const float* lob = LO + (size_t)q * 2048;
  float loa[16], lobv[16];
  #pragma unroll
  for (int t = 0; t < 16; ++t) {
    loa[t]  = lob[t * 128 + l];
    lobv[t] = lob[t * 128 + 64 + l];
  }
  const float wa = Wa[l], wb = Wa[64 + l];
  float sc[16];
  #pragma unroll
  for (int t = 0; t < 16; ++t) sc[t] = rsum64(loa[t] * wa + lobv[t] * wb) + ba[0];
  float mx = sc[0];
  #pragma unroll
  for (int t = 1; t < 16; ++t) mx = fmaxf(mx, sc[t]);
  float den = 0.f;
  #pragma unroll
  for (int t = 0; t < 16; ++t) { sc[t] = __expf(sc[t] - mx); den += sc[t]; }
  const float inv = 1.f / den;
  float ca = 0.f, cb = 0.f;
  #pragma unroll
  for (int t = 0; t < 16; ++t) {
    float wgt = sc[t] * inv;
    ca = fmaf(wgt, loa[t], ca);
    cb = fmaf(wgt, lobv[t], cb);
  }
  __shared__ float zsh[160];
  __shared__ float hsk[64];
  __shared__ float skin[16];
  zsh[l] = ca; zsh[64 + l] = cb;
  const int bb = q / 1000, nn = q - bb * 1000;
  if (l < 13) skin[l] = X[(size_t)((bb * 16 + 15) * 1000 + nn) * 32 + l];
  __syncthreads();
  float h1 = bs1[l];
  for (int c = 0; c < 13; ++c) h1 = fmaf(skin[c], HWT[c * 64 + l], h1);
  h1 = geluf(h1);
  hsk[l] = h1;
  __syncthreads();
  if (l < 32) {
    float a = bs2[l];
    for (int jj = 0; jj < 64; ++jj) a = fmaf(hsk[jj], HWT[832 + jj * 32 + l], a);
    zsh[128 + l] = a;
  }
  __syncthreads();
  float hh = bh1[l];
  for (int r = 0; r < 160; ++r) hh = fmaf(zsh[r], HWT[2880 + r * 64 + l], hh);
  hh = geluf(hh);
  float s = rsum64(hh * Wh2[l]);
  if (l == 0) out[q] = s + bh2[0];
}

// ---------------- launch ----------------
extern "C" void kernel_launch(void* const* d_in, const int* in_sizes, int n_in,
                              void* d_out, int out_size, void* d_ws, size_t ws_size,
                              hipStream_t stream)
{
  const float* x    = (const float*)d_in[0];
  const int*   ei   = (const int*)d_in[1];
  const float* Wp   = (const float*)d_in[2];
  const float* bp   = (const float*)d_in[3];
  const float* Wl1  = (const float*)d_in[4];
  const float* Wr1  = (const float*)d_in[5];
  const float* a1   = (const float*)d_in[6];
  const float* bg1  = (const float*)d_in[7];
  const float* g1   = (const float*)d_in[8];
  const float* be1  = (const float*)d_in[9];
  const float* m1   = (const float*)d_in[10];
  const float* v1   = (const float*)d_in[11];
  const float* Wl2  = (const float*)d_in[12];
  const float* Wr2  = (const float*)d_in[13];
  const float* a2   = (const float*)d_in[14];
  const float* bg2  = (const float*)d_in[15];
  const float* g2   = (const float*)d_in[16];
  const float* be2  = (const float*)d_in[17];
  const float* m2   = (const float*)d_in[18];
  const float* v2   = (const float*)d_in[19];
  const float* Wih0 = (const float*)d_in[20];
  const float* Whh0 = (const float*)d_in[21];
  const float* bih0 = (const float*)d_in[22];
  const float* bhh0 = (const float*)d_in[23];
  const float* Wih1 = (const float*)d_in[24];
  const float* Whh1 = (const float*)d_in[25];
  const float* bih1 = (const float*)d_in[26];
  const float* bhh1 = (const float*)d_in[27];
  const float* Wa   = (const float*)d_in[28];
  const float* ba   = (const float*)d_in[29];
  const float* Ws1  = (const float*)d_in[30];
  const float* bs1  = (const float*)d_in[31];
  const float* Ws2  = (const float*)d_in[32];
  const float* bs2  = (const float*)d_in[33];
  const float* Wh1  = (const float*)d_in[34];
  const float* bh1  = (const float*)d_in[35];
  const float* Wh2  = (const float*)d_in[36];
  const float* bh2  = (const float*)d_in[37];

  float* ws = (float*)d_ws;
  int* srcD   = (int*)(ws + O_SRCD);
  int* dstD   = (int*)(ws + O_DSTD);
  int* counts = (int*)(ws + O_COUNTS);
  int* offs   = (int*)(ws + O_OFFS);
  int* curs   = (int*)(ws + O_CURS);
  int* esrc   = (int*)(ws + O_EIDX);
  float* PW1  = ws + O_PW1;
  float* PW2  = ws + O_PW2;
  float* PLW  = ws + O_LW;
  float* BC   = ws + O_BCOMB;
  float* ABF  = ws + O_ABF;
  float* HWT  = ws + O_HWT;
  float* XL1  = ws + O_BIG0;
  float* XR1  = ws + O_BIG1;
  float* H1   = ws + O_BIG2;
  float* XP   = ws + O_BIG3;
  float* Hres = ws + O_BIG4;
  float* XL2  = ws + O_BIG0;             // reuse (XL1 dead)
  float* XR2  = ws + O_BIG0 + 8192000u;
  float* LOp  = ws + O_BIG1;             // reuse (XR1 dead)
  float* outp = (float*)d_out;

  prep_edges<<<67, 256, 0, stream>>>(ei, srcD, dstD, counts);
  hist_kernel<<<67, 256, 0, stream>>>(dstD, counts);
  scan_kernel<<<1, 1024, 0, stream>>>(counts, offs, curs);
  fill_kernel<<<67, 256, 0, stream>>>(srcD, dstD, curs, esrc);
  pack_kernel<<<1024, 256, 0, stream>>>(Wl1, Wr1, Wp, Wl2, Wr2,
      Wih0, Whh0, bih0, bhh0, Wih1, Whh1, bih1, bhh1,
      g1, be1, m1, v1, bg1, g2, be2, m2, v2, bg2,
      Ws1, Ws2, Wh1, PW1, PW2, PLW, BC, ABF, HWT);
  proj1_kernel<<<4000, 320, 0, stream>>>(x, PW1, bp, XL1, XR1, XP);
  gat1_kernel<<<dim3(250, 64), 256, 0, stream>>>(XL1, XR1, esrc, offs, a1, ABF, H1);
  proj2_kernel<<<4000, 256, 0, stream>>>(H1, PW2, XL2, XR2);
  gat2_kernel<<<dim3(250, 64), 256, 0, stream>>>(XL2, XR2, esrc, offs, a2, ABF, XP, Hres);
  lstm_kernel<<<250, 1024, 0, stream>>>(Hres, PLW, BC, LOp);
  attn_kernel<<<4000, 64, 0, stream>>>(LOp, x, Wa, ba, bs1, bs2, bh1, bh2, Wh2, HWT, outp);
}

// Round 4
// 1558.814 us; speedup vs baseline: 2.6712x; 1.0046x over previous
//
#include <hip/hip_runtime.h>

#define EPS_BN 1e-5f

// ---------------- workspace layout (float-unit offsets) ----------------
#define O_SRCD   0u
#define O_DSTD   17024u
#define O_COUNTS 34048u
#define O_OFFS   35072u
#define O_CURS   36096u
#define O_EIDX   37120u                    // esrc (src node id, CSR-ordered)
#define O_PW1    54144u                    // [32][640]  (Wl1T|Wr1T|WpT)
#define O_PW2    74624u                    // [256][256] (Wl2T|Wr2T)
#define O_LW     140160u                   // PLW: [2][16w][8q][4dk][64lane][4gate]
#define O_BCOMB  402304u                   // [2][128j][4]
#define O_ABF    403328u                   // A1(256)|B1(256)|A2(128)|B2(128)
#define O_HWT    404352u                   // Ws1T(832)|Ws2T(2048)|Wh1T(10240)
#define O_BIG0   417536u                   // XL1  | later XL2,XR2
#define O_BIG1   (O_BIG0 + 16384000u)      // XR1  | later LO
#define O_BIG2   (O_BIG1 + 16384000u)      // H1
#define O_BIG3   (O_BIG2 + 16384000u)      // XP
#define O_BIG4   (O_BIG3 + 8192000u)       // Hres

__device__ __forceinline__ float rsum32(float p) {
  p += __shfl_xor(p, 1);  p += __shfl_xor(p, 2);  p += __shfl_xor(p, 4);
  p += __shfl_xor(p, 8);  p += __shfl_xor(p, 16); return p;
}
__device__ __forceinline__ float rsum64(float p) {
  p = rsum32(p); p += __shfl_xor(p, 32); return p;
}
__device__ __forceinline__ float lrelu(float x) { return x > 0.f ? x : 0.2f * x; }
__device__ __forceinline__ float eluf(float x)  { return x > 0.f ? x : expm1f(x); }
__device__ __forceinline__ float geluf(float x) { return 0.5f * x * (1.f + erff(x * 0.70710678118654752f)); }

// ---------------- prep kernels ----------------
__global__ void prep_edges(const int* __restrict__ ei, int* __restrict__ srcD,
                           int* __restrict__ dstD, int* __restrict__ counts) {
  int i = blockIdx.x * 256 + threadIdx.x;
  if (i < 1024) counts[i] = 0;
  if (i < 17000) {
    int s = (i < 16000) ? ei[i] : (i - 16000);
    int d = (i < 16000) ? ei[16000 + i] : (i - 16000);
    srcD[i] = s; dstD[i] = d;
  }
}
__global__ void hist_kernel(const int* __restrict__ dstD, int* __restrict__ counts) {
  int i = blockIdx.x * 256 + threadIdx.x;
  if (i < 17000) atomicAdd(&counts[dstD[i]], 1);
}
__global__ void scan_kernel(const int* __restrict__ counts, int* __restrict__ offs,
                            int* __restrict__ curs) {
  __shared__ int sh[1024];
  int i = threadIdx.x;
  int v = (i < 1000) ? counts[i] : 0;
  sh[i] = v;
  __syncthreads();
  for (int d = 1; d < 1024; d <<= 1) {
    int t = (i >= d) ? sh[i - d] : 0;
    __syncthreads();
    sh[i] += t;
    __syncthreads();
  }
  if (i < 1000) { offs[i + 1] = sh[i]; curs[i] = sh[i] - v; }
  if (i == 0) offs[0] = 0;
}
__global__ void fill_kernel(const int* __restrict__ srcD, const int* __restrict__ dstD,
                            int* __restrict__ curs, int* __restrict__ esrc) {
  int i = blockIdx.x * 256 + threadIdx.x;
  if (i < 17000) { int p = atomicAdd(&curs[dstD[i]], 1); esrc[p] = srcD[i]; }
}

__global__ void pack_kernel(
    const float* __restrict__ Wl1, const float* __restrict__ Wr1, const float* __restrict__ Wp,
    const float* __restrict__ Wl2, const float* __restrict__ Wr2,
    const float* __restrict__ Wih0, const float* __restrict__ Whh0,
    const float* __restrict__ bih0, const float* __restrict__ bhh0,
    const float* __restrict__ Wih1, const float* __restrict__ Whh1,
    const float* __restrict__ bih1, const float* __restrict__ bhh1,
    const float* __restrict__ g1, const float* __restrict__ be1, const float* __restrict__ m1,
    const float* __restrict__ v1, const float* __restrict__ bg1,
    const float* __restrict__ g2, const float* __restrict__ be2, const float* __restrict__ m2,
    const float* __restrict__ v2, const float* __restrict__ bg2,
    const float* __restrict__ Ws1, const float* __restrict__ Ws2, const float* __restrict__ Wh1,
    float* __restrict__ PW1, float* __restrict__ PW2, float* __restrict__ PLW,
    float* __restrict__ BC, float* __restrict__ ABF, float* __restrict__ HWT)
{
  int i = blockIdx.x * 256 + threadIdx.x;
  if (i < 262144) {  // LSTM packed weights: [L][w16][q8][dk4][lane64][gate4]
    int gate = i & 3, lane = (i >> 2) & 63, dk = (i >> 8) & 3,
        q = (i >> 10) & 7, w = (i >> 13) & 15, L = (i >> 17) & 1;
    int jlo = lane & 7, pp = lane >> 3;
    int mat = pp >> 2, kq = pp & 3;
    int jj = (w << 3) + jlo;
    int kk = (kq << 5) + (q << 2) + dk;
    const float* Wih = L ? Wih1 : Wih0;
    const float* Whh = L ? Whh1 : Whh0;
    PLW[i] = mat ? Whh[(gate * 128 + jj) * 128 + kk]
                 : Wih[(gate * 128 + jj) * 128 + kk];
  }
  if (i < 65536) { int c = i & 255, k = i >> 8;
    PW2[i] = (c < 128) ? Wl2[c * 256 + k] : Wr2[(c - 128) * 256 + k]; }
  if (i < 20480) { int g = i % 640, k = i / 640;
    PW1[i] = (g < 256) ? Wl1[g * 32 + k] : (g < 512) ? Wr1[(g - 256) * 32 + k]
                                                     : Wp[(g - 512) * 32 + k]; }
  if (i < 1024) { int u = i & 3, jj = (i >> 2) & 127, L = i >> 9;
    BC[i] = (L ? bih1 : bih0)[u * 128 + jj] + (L ? bhh1 : bhh0)[u * 128 + jj]; }
  if (i < 768) {
    if (i < 256) ABF[i] = g1[i] * rsqrtf(v1[i] + EPS_BN);
    else if (i < 512) { int c = i - 256; float a = g1[c] * rsqrtf(v1[c] + EPS_BN);
      ABF[i] = (bg1[c] - m1[c]) * a + be1[c]; }
    else if (i < 640) { int c = i - 512; ABF[i] = g2[c] * rsqrtf(v2[c] + EPS_BN); }
    else { int c = i - 640; float a = g2[c] * rsqrtf(v2[c] + EPS_BN);
      ABF[i] = (bg2[c] - m2[c]) * a + be2[c]; }
  }
  if (i < 13120) {
    if (i < 832) { int l = i & 63, c = i >> 6; HWT[i] = Ws1[l * 13 + c]; }
    else if (i < 2880) { int k = i - 832; int l = k & 31, jj = k >> 5; HWT[i] = Ws2[l * 64 + jj]; }
    else { int k = i - 2880; int l = k & 63, r = k >> 6; HWT[i] = Wh1[l * 160 + r]; }
  }
}

// ---------------- projection 1: x -> xl1(256) | xr1(256) | xp(128) ----------------
__global__ __launch_bounds__(320)
void proj1_kernel(const float* __restrict__ X, const float* __restrict__ PW1,
                  const float* __restrict__ bp,
                  float* __restrict__ XL1, float* __restrict__ XR1, float* __restrict__ XP)
{
  __shared__ __align__(16) float xs[32][16];
  const int tid = threadIdx.x;
  const int r0 = blockIdx.x * 16;
  for (int el = tid; el < 512; el += 320) {
    int r = el >> 5, k = el & 31;
    xs[k][r] = X[(size_t)(r0 + r) * 32 + k];
  }
  __syncthreads();
  const int gA = tid, gB = tid + 320;
  float accA[16], accB[16];
  const float iB = (gB >= 512) ? bp[gB - 512] : 0.f;
  #pragma unroll
  for (int r = 0; r < 16; ++r) { accA[r] = 0.f; accB[r] = iB; }
  for (int k = 0; k < 32; ++k) {
    float wA = PW1[k * 640 + gA], wB = PW1[k * 640 + gB];
    float xv[16];
    #pragma unroll
    for (int q = 0; q < 4; ++q)
      *reinterpret_cast<float4*>(&xv[q * 4]) = *reinterpret_cast<const float4*>(&xs[k][q * 4]);
    #pragma unroll
    for (int r = 0; r < 16; ++r) {
      accA[r] = fmaf(wA, xv[r], accA[r]);
      accB[r] = fmaf(wB, xv[r], accB[r]);
    }
  }
  for (int r = 0; r < 16; ++r) {
    size_t row = r0 + r;
    if (gA < 256) XL1[row * 256 + gA] = accA[r];
    else          XR1[row * 256 + (gA - 256)] = accA[r];
    if (gB < 512) XR1[row * 256 + (gB - 256)] = accB[r];
    else          XP[row * 128 + (gB - 512)] = accB[r];
  }
}

// ---------------- GAT layer 1 fused (2 heads, d=128) ----------------
__global__ __launch_bounds__(256)
void gat1_kernel(const float* __restrict__ XL, const float* __restrict__ XR,
                 const int* __restrict__ esrc,
                 const int* __restrict__ offs, const float* __restrict__ a1,
                 const float* __restrict__ ABF, float* __restrict__ H1)
{
  const int lane = threadIdx.x & 63;
  const int wv = threadIdx.x >> 6;
  const int n = blockIdx.x * 4 + wv;
  const int b = blockIdx.y;
  const int half = lane >> 5;
  __shared__ float lsh[4][128];
  const int beg = offs[n];
  const int deg = offs[n + 1] - beg;
  const float4 a4 = reinterpret_cast<const float4*>(a1)[lane];
  const float4* XLb = reinterpret_cast<const float4*>(XL) + (size_t)b * 64000;
  const float4 xr4 = reinterpret_cast<const float4*>(XR + (size_t)(b * 1000 + n) * 256)[lane];
  float m = -INFINITY, ssum = 0.f;
  {
    int sC = esrc[beg];
    float4 xc = XLb[(size_t)sC * 64 + lane];
    for (int i = 0; i < deg; ++i) {
      int nx = (i + 1 < deg) ? (i + 1) : i;
      int sN = esrc[beg + nx];
      float4 xn = XLb[(size_t)sN * 64 + lane];
      float p = lrelu(xc.x + xr4.x) * a4.x + lrelu(xc.y + xr4.y) * a4.y
              + lrelu(xc.z + xr4.z) * a4.z + lrelu(xc.w + xr4.w) * a4.w;
      p = rsum32(p);
      if (i < 64 && (lane & 31) == 0) lsh[wv][2 * i + half] = p;
      float mn = fmaxf(m, p);
      ssum = ssum * __expf(m - mn) + __expf(p - mn);
      m = mn;
      xc = xn;
    }
  }
  const float inv = 1.f / ssum;
  __builtin_amdgcn_wave_barrier();
  float4 acc = make_float4(0.f, 0.f, 0.f, 0.f);
  {
    int sC = esrc[beg];
    float4 xc = XLb[(size_t)sC * 64 + lane];
    for (int i = 0; i < deg; ++i) {
      int nx = (i + 1 < deg) ? (i + 1) : i;
      int sN = esrc[beg + nx];
      float4 xn = XLb[(size_t)sN * 64 + lane];
      float lg;
      if (i < 64) lg = lsh[wv][2 * i + half];
      else {
        float p = lrelu(xc.x + xr4.x) * a4.x + lrelu(xc.y + xr4.y) * a4.y
                + lrelu(xc.z + xr4.z) * a4.z + lrelu(xc.w + xr4.w) * a4.w;
        lg = rsum32(p);
      }
      const float al = __expf(lg - m) * inv;
      acc.x = fmaf(al, xc.x, acc.x);
      acc.y = fmaf(al, xc.y, acc.y);
      acc.z = fmaf(al, xc.z, acc.z);
      acc.w = fmaf(al, xc.w, acc.w);
      xc = xn;
    }
  }
  const float4 A4 = reinterpret_cast<const float4*>(ABF)[lane];
  const float4 B4 = reinterpret_cast<const float4*>(ABF + 256)[lane];
  float4 o;
  o.x = eluf(fmaf(acc.x, A4.x, B4.x));
  o.y = eluf(fmaf(acc.y, A4.y, B4.y));
  o.z = eluf(fmaf(acc.z, A4.z, B4.z));
  o.w = eluf(fmaf(acc.w, A4.w, B4.w));
  reinterpret_cast<float4*>(H1 + (size_t)(b * 1000 + n) * 256)[lane] = o;
}

// ---------------- projection 2: h1(256) -> xl2(128)|xr2(128) ----------------
__global__ __launch_bounds__(256)
void proj2_kernel(const float* __restrict__ H1, const float* __restrict__ PW2,
                  float* __restrict__ XL2, float* __restrict__ XR2)
{
  __shared__ __align__(16) float xs[256][20];
  const int tid = threadIdx.x;
  const int r0 = blockIdx.x * 16;
  for (int el = tid; el < 4096; el += 256) {
    int k = el & 255, r = el >> 8;
    xs[k][r] = H1[(size_t)(r0 + r) * 256 + k];
  }
  __syncthreads();
  float acc[16];
  #pragma unroll
  for (int r = 0; r < 16; ++r) acc[r] = 0.f;
  for (int k = 0; k < 256; ++k) {
    float wgt = PW2[k * 256 + tid];
    float xv[16];
    #pragma unroll
    for (int q = 0; q < 4; ++q)
      *reinterpret_cast<float4*>(&xv[q * 4]) = *reinterpret_cast<const float4*>(&xs[k][q * 4]);
    #pragma unroll
    for (int r = 0; r < 16; ++r) acc[r] = fmaf(wgt, xv[r], acc[r]);
  }
  float* dst = (tid < 128) ? XL2 : XR2;
  const int col = tid & 127;
  for (int r = 0; r < 16; ++r)
    dst[(size_t)(r0 + r) * 128 + col] = acc[r];
}

// ---------------- GAT layer 2 fused (1 head) + BN/ELU + residual ----------------
__global__ __launch_bounds__(256)
void gat2_kernel(const float* __restrict__ XL, const float* __restrict__ XR,
                 const int* __restrict__ esrc,
                 const int* __restrict__ offs, const float* __restrict__ a2,
                 const float* __restrict__ ABF, const float* __restrict__ XP,
                 float* __restrict__ Hout)
{
  const int lane = threadIdx.x & 63;
  const int wv = threadIdx.x >> 6;
  const int n = blockIdx.x * 4 + wv;
  const int b = blockIdx.y;
  __shared__ float lsh[4][96];
  const int beg = offs[n];
  const int deg = offs[n + 1] - beg;
  const float2 av = reinterpret_cast<const float2*>(a2)[lane];
  const float2* XLb = reinterpret_cast<const float2*>(XL) + (size_t)b * 64000;
  const float2 xr2 = reinterpret_cast<const float2*>(XR + (size_t)(b * 1000 + n) * 128)[lane];
  float m = -INFINITY, ssum = 0.f;
  {
    int sC = esrc[beg];
    float2 xc = XLb[(size_t)sC * 64 + lane];
    for (int i = 0; i < deg; ++i) {
      int nx = (i + 1 < deg) ? (i + 1) : i;
      int sN = esrc[beg + nx];
      float2 xn = XLb[(size_t)sN * 64 + lane];
      float p = lrelu(xc.x + xr2.x) * av.x + lrelu(xc.y + xr2.y) * av.y;
      p = rsum64(p);
      if (i < 96 && lane == 0) lsh[wv][i] = p;
      float mn = fmaxf(m, p);
      ssum = ssum * __expf(m - mn) + __expf(p - mn);
      m = mn;
      xc = xn;
    }
  }
  const float inv = 1.f / ssum;
  __builtin_amdgcn_wave_barrier();
  float2 acc = make_float2(0.f, 0.f);
  {
    int sC = esrc[beg];
    float2 xc = XLb[(size_t)sC * 64 + lane];
    for (int i = 0; i < deg; ++i) {
      int nx = (i + 1 < deg) ? (i + 1) : i;
      int sN = esrc[beg + nx];
      float2 xn = XLb[(size_t)sN * 64 + lane];
      float lg;
      if (i < 96) lg = lsh[wv][i];
      else {
        float p = lrelu(xc.x + xr2.x) * av.x + lrelu(xc.y + xr2.y) * av.y;
        lg = rsum64(p);
      }
      const float al = __expf(lg - m) * inv;
      acc.x = fmaf(al, xc.x, acc.x);
      acc.y = fmaf(al, xc.y, acc.y);
      xc = xn;
    }
  }
  const float2 A2 = reinterpret_cast<const float2*>(ABF + 512)[lane];
  const float2 B2 = reinterpret_cast<const float2*>(ABF + 640)[lane];
  const float2 xp = reinterpret_cast<const float2*>(XP + (size_t)(b * 1000 + n) * 128)[lane];
  float2 o;
  o.x = eluf(fmaf(acc.x, A2.x, B2.x)) + xp.x;
  o.y = eluf(fmaf(acc.y, A2.y, B2.y)) + xp.y;
  reinterpret_cast<float2*>(Hout + (size_t)(b * 1000 + n) * 128)[lane] = o;
}

// ---------------- fused 2-layer LSTM (8-way k-split, butterfly reduce) ----------------
#define FMA4(A, W, S) { (A).x = fmaf((W).x, (S), (A).x); (A).y = fmaf((W).y, (S), (A).y); \
                        (A).z = fmaf((W).z, (S), (A).z); (A).w = fmaf((W).w, (S), (A).w); }
#define AD4(a, b) { (a).x += (b).x; (a).y += (b).y; (a).z += (b).z; (a).w += (b).w; }
#define LROW 140

__device__ __forceinline__ float4 shflx4(float4 v, int msk) {
  float4 r;
  r.x = __shfl_xor(v.x, msk); r.y = __shfl_xor(v.y, msk);
  r.z = __shfl_xor(v.z, msk); r.w = __shfl_xor(v.w, msk);
  return r;
}

// weights double-buffered 1 q-step ahead; acc g[16] float4 stays register-resident
__device__ __forceinline__ void gates8(const float4* __restrict__ wb,
                                       const float* XS, int xoff, float4 (&g)[16])
{
  float4 w0 = wb[0], w1 = wb[64], w2 = wb[128], w3 = wb[192];
  #pragma unroll
  for (int q = 0; q < 8; ++q) {
    float4 c0 = w0, c1 = w1, c2 = w2, c3 = w3;
    if (q < 7) {
      const float4* nq = wb + (q + 1) * 256;
      w0 = nq[0]; w1 = nq[64]; w2 = nq[128]; w3 = nq[192];
    }
    const float* xp = XS + xoff + (q << 2);
    #pragma unroll
    for (int s = 0; s < 16; ++s) {
      float4 xv = *reinterpret_cast<const float4*>(xp + s * LROW);
      FMA4(g[s], c0, xv.x);
      FMA4(g[s], c1, xv.y);
      FMA4(g[s], c2, xv.z);
      FMA4(g[s], c3, xv.w);
    }
  }
}

// narrowing 3-round butterfly over p = lane>>3; result: seqs 2p, 2p+1
__device__ __forceinline__ void reduce8(float4 (&g)[16], int lane, float4& ga, float4& gb)
{
  const bool b4 = (lane & 32) != 0, b2 = (lane & 16) != 0, b1 = (lane & 8) != 0;
  float4 t[8];
  #pragma unroll
  for (int i = 0; i < 8; ++i) {
    float4 keep = b4 ? g[8 + i] : g[i];
    float4 send = b4 ? g[i] : g[8 + i];
    float4 r = shflx4(send, 32);
    AD4(keep, r); t[i] = keep;
  }
  float4 u[4];
  #pragma unroll
  for (int i = 0; i < 4; ++i) {
    float4 keep = b2 ? t[4 + i] : t[i];
    float4 send = b2 ? t[i] : t[4 + i];
    float4 r = shflx4(send, 16);
    AD4(keep, r); u[i] = keep;
  }
  {
    float4 keep = b1 ? u[2] : u[0];
    float4 send = b1 ? u[0] : u[2];
    float4 r = shflx4(send, 8);
    AD4(keep, r); ga = keep;
  }
  {
    float4 keep = b1 ? u[3] : u[1];
    float4 send = b1 ? u[1] : u[3];
    float4 r = shflx4(send, 8);
    AD4(keep, r); gb = keep;
  }
}

__device__ __forceinline__ float cellf(float4 g, float& c) {
  const float ig = 1.f / (1.f + __expf(-g.x));
  const float fg = 1.f / (1.f + __expf(-g.y));
  const float gg = tanhf(g.z);
  const float og = 1.f / (1.f + __expf(-g.w));
  c = fmaf(fg, c, ig * gg);
  return og * tanhf(c);
}

// 16 waves/block, 1 block/CU. amdgpu_waves_per_eu(4,4) pins the RA target to
// exactly 4 waves/EU -> 128-VGPR budget. Bare launch_bounds(1024[,4]) let the
// RA chase 8 waves/EU (LDS allows 2 blocks/CU) and spill ~2 GB to scratch.
__global__ __launch_bounds__(1024)
__attribute__((amdgpu_waves_per_eu(4, 4)))
void lstm_kernel(const float* __restrict__ Hin, const float* __restrict__ PLW,
                 const float* __restrict__ BC, float* __restrict__ LO)
{
  __shared__ __align__(16) float xb[2][16][LROW];
  __shared__ __align__(16) float h1s[16][LROW];
  __shared__ __align__(16) float h2b[2][16][LROW];
  const int tid = threadIdx.x;
  const int lane = tid & 63;
  const int w = tid >> 6;                 // 0..15 (wave id; 8 hidden units per wave)
  const int jlo = lane & 7;
  const int p = lane >> 3;                // 0..7: (k,mat) slice; mat = p>>2
  const int j = (w << 3) + jlo;           // hidden unit 0..127
  const int xoff = 36 * (p & 3);          // skewed column base for this k-chunk
  const bool hi = p >= 4;                 // hh side
  const int jo = j + ((j >> 5) << 2);     // skewed LDS column for unit j
  const int q0 = blockIdx.x << 4;
  const int s0 = 2 * p;                   // owned seqs after reduce
  for (int i = tid; i < 16 * LROW; i += 1024) {
    (&h1s[0][0])[i] = 0.f;
    (&h2b[0][0][0])[i] = 0.f;
  }
  #pragma unroll
  for (int c = 0; c < 2; ++c) {
    int el = (c << 10) + tid;
    int s = el >> 7, k = el & 127;
    xb[0][s][k + ((k >> 5) << 2)] = Hin[((size_t)(((q0 + s) << 4))) * 128 + k];
  }
  const float4 b1 = *reinterpret_cast<const float4*>(BC + (j << 2));
  const float4 b2 = *reinterpret_cast<const float4*>(BC + 512 + (j << 2));
  const float4* PLW4 = reinterpret_cast<const float4*>(PLW);
  const float4* wb1 = PLW4 + (w << 11) + lane;
  const float4* wb2 = wb1 + 32768;
  float c1a = 0.f, c1b = 0.f, c2a = 0.f, c2b = 0.f;
  __syncthreads();
  int cur = 0;
  for (int t = 0; t < 16; ++t) {
    if (t < 15) {
      #pragma unroll
      for (int c = 0; c < 2; ++c) {
        int el = (c << 10) + tid;
        int s = el >> 7, k = el & 127;
        xb[cur ^ 1][s][k + ((k >> 5) << 2)] =
            Hin[((size_t)(((q0 + s) << 4) + (t + 1))) * 128 + k];
      }
    }
    float4 g[16];
    #pragma unroll
    for (int s = 0; s < 16; ++s) g[s] = make_float4(0.f, 0.f, 0.f, 0.f);
    gates8(wb1, hi ? &h1s[0][0] : &xb[cur][0][0], xoff, g);
    float4 ga, gb;
    reduce8(g, lane, ga, gb);
    AD4(ga, b1); AD4(gb, b1);
    float h1a = cellf(ga, c1a), h1b = cellf(gb, c1b);
    __syncthreads();                       // (A) all gates-1 reads done
    h1s[s0][jo] = h1a;
    h1s[s0 + 1][jo] = h1b;
    __syncthreads();                       // (B) h1 visible
    #pragma unroll
    for (int s = 0; s < 16; ++s) g[s] = make_float4(0.f, 0.f, 0.f, 0.f);
    gates8(wb2, hi ? &h2b[cur][0][0] : &h1s[0][0], xoff, g);
    reduce8(g, lane, ga, gb);
    AD4(ga, b2); AD4(gb, b2);
    float h2x = cellf(ga, c2a), h2y = cellf(gb, c2b);
    h2b[cur ^ 1][s0][jo] = h2x;
    h2b[cur ^ 1][s0 + 1][jo] = h2y;
    LO[((size_t)(((q0 + s0) << 4) + t)) * 128 + j] = h2x;
    LO[((size_t)(((q0 + s0 + 1) << 4) + t)) * 128 + j] = h2y;
    cur ^= 1;
  }
}

// ---------------- attention pool + skip MLP + head ----------------
__global__ __launch_bounds__(64)
void attn_kernel(const float* __restrict__ LO, const float* __restrict__ X,
                 const float* __restrict__ Wa, const float* __restrict__ ba,
                 const float* __restrict__ bs1, const float* __restrict__ bs2,
                 const float* __restrict__ bh1, const float* __restrict__ bh2,
                 const float* __restrict__ Wh2, const float* __restrict__ HWT,
                 float* __restrict__ out)
{
  const int q = blockIdx.x, l = threadIdx.x;
  const float* lob = LO + (size_t)q * 2048;
  float loa[16], lobv[16];
  #pragma unroll
  for (int t = 0; t < 16; ++t) {
    loa[t]  = lob[t * 128 + l];
    lobv[t] = lob[t * 128 + 64 + l];
  }
  const float wa = Wa[l], wb = Wa[64 + l];
  float sc[16];
  #pragma unroll
  for (int t = 0; t < 16; ++t) sc[t] = rsum64(loa[t] * wa + lobv[t] * wb) + ba[0];
  float mx = sc[0];
  #pragma unroll
  for (int t = 1; t < 16; ++t) mx = fmaxf(mx, sc[t]);
  float den = 0.f;
  #pragma unroll
  for (int t = 0; t < 16; ++t) { sc[t] = __expf(sc[t] - mx); den += sc[t]; }
  const float inv = 1.f / den;
  float ca = 0.f, cb = 0.f;
  #pragma unroll
  for (int t = 0; t < 16; ++t) {
    float wgt = sc[t] * inv;
    ca = fmaf(wgt, loa[t], ca);
    cb = fmaf(wgt, lobv[t], cb);
  }
  __shared__ float zsh[160];
  __shared__ float hsk[64];
  __shared__ float skin[16];
  zsh[l] = ca; zsh[64 + l] = cb;
  const int bb = q / 1000, nn = q - bb * 1000;
  if (l < 13) skin[l] = X[(size_t)((bb * 16 + 15) * 1000 + nn) * 32 + l];
  __syncthreads();
  float h1 = bs1[l];
  for (int c = 0; c < 13; ++c) h1 = fmaf(skin[c], HWT[c * 64 + l], h1);
  h1 = geluf(h1);
  hsk[l] = h1;
  __syncthreads();
  if (l < 32) {
    float a = bs2[l];
    for (int jj = 0; jj < 64; ++jj) a = fmaf(hsk[jj], HWT[832 + jj * 32 + l], a);
    zsh[128 + l] = a;
  }
  __syncthreads();
  float hh = bh1[l];
  for (int r = 0; r < 160; ++r) hh = fmaf(zsh[r], HWT[2880 + r * 64 + l], hh);
  hh = geluf(hh);
  float s = rsum64(hh * Wh2[l]);
  if (l == 0) out[q] = s + bh2[0];
}

// ---------------- launch ----------------
extern "C" void kernel_launch(void* const* d_in, const int* in_sizes, int n_in,
                              void* d_out, int out_size, void* d_ws, size_t ws_size,
                              hipStream_t stream)
{
  const float* x    = (const float*)d_in[0];
  const int*   ei   = (const int*)d_in[1];
  const float* Wp   = (const float*)d_in[2];
  const float* bp   = (const float*)d_in[3];
  const float* Wl1  = (const float*)d_in[4];
  const float* Wr1  = (const float*)d_in[5];
  const float* a1   = (const float*)d_in[6];
  const float* bg1  = (const float*)d_in[7];
  const float* g1   = (const float*)d_in[8];
  const float* be1  = (const float*)d_in[9];
  const float* m1   = (const float*)d_in[10];
  const float* v1   = (const float*)d_in[11];
  const float* Wl2  = (const float*)d_in[12];
  const float* Wr2  = (const float*)d_in[13];
  const float* a2   = (const float*)d_in[14];
  const float* bg2  = (const float*)d_in[15];
  const float* g2   = (const float*)d_in[16];
  const float* be2  = (const float*)d_in[17];
  const float* m2   = (const float*)d_in[18];
  const float* v2   = (const float*)d_in[19];
  const float* Wih0 = (const float*)d_in[20];
  const float* Whh0 = (const float*)d_in[21];
  const float* bih0 = (const float*)d_in[22];
  const float* bhh0 = (const float*)d_in[23];
  const float* Wih1 = (const float*)d_in[24];
  const float* Whh1 = (const float*)d_in[25];
  const float* bih1 = (const float*)d_in[26];
  const float* bhh1 = (const float*)d_in[27];
  const float* Wa   = (const float*)d_in[28];
  const float* ba   = (const float*)d_in[29];
  const float* Ws1  = (const float*)d_in[30];
  const float* bs1  = (const float*)d_in[31];
  const float* Ws2  = (const float*)d_in[32];
  const float* bs2  = (const float*)d_in[33];
  const float* Wh1  = (const float*)d_in[34];
  const float* bh1  = (const float*)d_in[35];
  const float* Wh2  = (const float*)d_in[36];
  const float* bh2  = (const float*)d_in[37];

  float* ws = (float*)d_ws;
  int* srcD   = (int*)(ws + O_SRCD);
  int* dstD   = (int*)(ws + O_DSTD);
  int* counts = (int*)(ws + O_COUNTS);
  int* offs   = (int*)(ws + O_OFFS);
  int* curs   = (int*)(ws + O_CURS);
  int* esrc   = (int*)(ws + O_EIDX);
  float* PW1  = ws + O_PW1;
  float* PW2  = ws + O_PW2;
  float* PLW  = ws + O_LW;
  float* BC   = ws + O_BCOMB;
  float* ABF  = ws + O_ABF;
  float* HWT  = ws + O_HWT;
  float* XL1  = ws + O_BIG0;
  float* XR1  = ws + O_BIG1;
  float* H1   = ws + O_BIG2;
  float* XP   = ws + O_BIG3;
  float* Hres = ws + O_BIG4;
  float* XL2  = ws + O_BIG0;             // reuse (XL1 dead)
  float* XR2  = ws + O_BIG0 + 8192000u;
  float* LOp  = ws + O_BIG1;             // reuse (XR1 dead)
  float* outp = (float*)d_out;

  prep_edges<<<67, 256, 0, stream>>>(ei, srcD, dstD, counts);
  hist_kernel<<<67, 256, 0, stream>>>(dstD, counts);
  scan_kernel<<<1, 1024, 0, stream>>>(counts, offs, curs);
  fill_kernel<<<67, 256, 0, stream>>>(srcD, dstD, curs, esrc);
  pack_kernel<<<1024, 256, 0, stream>>>(Wl1, Wr1, Wp, Wl2, Wr2,
      Wih0, Whh0, bih0, bhh0, Wih1, Whh1, bih1, bhh1,
      g1, be1, m1, v1, bg1, g2, be2, m2, v2, bg2,
      Ws1, Ws2, Wh1, PW1, PW2, PLW, BC, ABF, HWT);
  proj1_kernel<<<4000, 320, 0, stream>>>(x, PW1, bp, XL1, XR1, XP);
  gat1_kernel<<<dim3(250, 64), 256, 0, stream>>>(XL1, XR1, esrc, offs, a1, ABF, H1);
  proj2_kernel<<<4000, 256, 0, stream>>>(H1, PW2, XL2, XR2);
  gat2_kernel<<<dim3(250, 64), 256, 0, stream>>>(XL2, XR2, esrc, offs, a2, ABF, XP, Hres);
  lstm_kernel<<<250, 1024, 0, stream>>>(Hres, PLW, BC, LOp);
  attn_kernel<<<4000, 64, 0, stream>>>(LOp, x, Wa, ba, bs1, bs2, bh1, bh2, Wh2, HWT, outp);
}

// Round 5
// 1147.127 us; speedup vs baseline: 3.6299x; 1.3589x over previous
//
#include <hip/hip_runtime.h>

#define EPS_BN 1e-5f

// ---------------- workspace layout (float-unit offsets) ----------------
#define O_SRCD   0u
#define O_DSTD   17024u
#define O_COUNTS 34048u
#define O_OFFS   35072u
#define O_CURS   36096u
#define O_EIDX   37120u                    // esrc (src node id, CSR-ordered)
#define O_PW1    54144u                    // [32][640]  (Wl1T|Wr1T|WpT)
#define O_PW2    74624u                    // [256][256] (Wl2T|Wr2T)
#define O_LW     140160u                   // PLW: [2][16w][8q][4dk][64lane][4gate]
#define O_BCOMB  402304u                   // [2][128j][4]
#define O_ABF    403328u                   // A1(256)|B1(256)|A2(128)|B2(128)
#define O_HWT    404352u                   // Ws1T(832)|Ws2T(2048)|Wh1T(10240)
#define O_BIG0   417536u                   // XL1  | later XL2,XR2
#define O_BIG1   (O_BIG0 + 16384000u)      // XR1  | later LO
#define O_BIG2   (O_BIG1 + 16384000u)      // H1
#define O_BIG3   (O_BIG2 + 16384000u)      // XP
#define O_BIG4   (O_BIG3 + 8192000u)       // Hres

__device__ __forceinline__ float rsum32(float p) {
  p += __shfl_xor(p, 1);  p += __shfl_xor(p, 2);  p += __shfl_xor(p, 4);
  p += __shfl_xor(p, 8);  p += __shfl_xor(p, 16); return p;
}
__device__ __forceinline__ float rsum64(float p) {
  p = rsum32(p); p += __shfl_xor(p, 32); return p;
}
__device__ __forceinline__ float lrelu(float x) { return x > 0.f ? x : 0.2f * x; }
__device__ __forceinline__ float eluf(float x)  { return x > 0.f ? x : expm1f(x); }
__device__ __forceinline__ float geluf(float x) { return 0.5f * x * (1.f + erff(x * 0.70710678118654752f)); }

// ---------------- prep kernels ----------------
__global__ void prep_edges(const int* __restrict__ ei, int* __restrict__ srcD,
                           int* __restrict__ dstD, int* __restrict__ counts) {
  int i = blockIdx.x * 256 + threadIdx.x;
  if (i < 1024) counts[i] = 0;
  if (i < 17000) {
    int s = (i < 16000) ? ei[i] : (i - 16000);
    int d = (i < 16000) ? ei[16000 + i] : (i - 16000);
    srcD[i] = s; dstD[i] = d;
  }
}
__global__ void hist_kernel(const int* __restrict__ dstD, int* __restrict__ counts) {
  int i = blockIdx.x * 256 + threadIdx.x;
  if (i < 17000) atomicAdd(&counts[dstD[i]], 1);
}
__global__ void scan_kernel(const int* __restrict__ counts, int* __restrict__ offs,
                            int* __restrict__ curs) {
  __shared__ int sh[1024];
  int i = threadIdx.x;
  int v = (i < 1000) ? counts[i] : 0;
  sh[i] = v;
  __syncthreads();
  for (int d = 1; d < 1024; d <<= 1) {
    int t = (i >= d) ? sh[i - d] : 0;
    __syncthreads();
    sh[i] += t;
    __syncthreads();
  }
  if (i < 1000) { offs[i + 1] = sh[i]; curs[i] = sh[i] - v; }
  if (i == 0) offs[0] = 0;
}
__global__ void fill_kernel(const int* __restrict__ srcD, const int* __restrict__ dstD,
                            int* __restrict__ curs, int* __restrict__ esrc) {
  int i = blockIdx.x * 256 + threadIdx.x;
  if (i < 17000) { int p = atomicAdd(&curs[dstD[i]], 1); esrc[p] = srcD[i]; }
}

__global__ void pack_kernel(
    const float* __restrict__ Wl1, const float* __restrict__ Wr1, const float* __restrict__ Wp,
    const float* __restrict__ Wl2, const float* __restrict__ Wr2,
    const float* __restrict__ Wih0, const float* __restrict__ Whh0,
    const float* __restrict__ bih0, const float* __restrict__ bhh0,
    const float* __restrict__ Wih1, const float* __restrict__ Whh1,
    const float* __restrict__ bih1, const float* __restrict__ bhh1,
    const float* __restrict__ g1, const float* __restrict__ be1, const float* __restrict__ m1,
    const float* __restrict__ v1, const float* __restrict__ bg1,
    const float* __restrict__ g2, const float* __restrict__ be2, const float* __restrict__ m2,
    const float* __restrict__ v2, const float* __restrict__ bg2,
    const float* __restrict__ Ws1, const float* __restrict__ Ws2, const float* __restrict__ Wh1,
    float* __restrict__ PW1, float* __restrict__ PW2, float* __restrict__ PLW,
    float* __restrict__ BC, float* __restrict__ ABF, float* __restrict__ HWT)
{
  int i = blockIdx.x * 256 + threadIdx.x;
  if (i < 262144) {  // LSTM packed weights: [L][w16][q8][dk4][lane64][gate4]
    int gate = i & 3, lane = (i >> 2) & 63, dk = (i >> 8) & 3,
        q = (i >> 10) & 7, w = (i >> 13) & 15, L = (i >> 17) & 1;
    int jlo = lane & 7, pp = lane >> 3;
    int mat = pp >> 2, kq = pp & 3;
    int jj = (w << 3) + jlo;
    int kk = (kq << 5) + (q << 2) + dk;
    const float* Wih = L ? Wih1 : Wih0;
    const float* Whh = L ? Whh1 : Whh0;
    PLW[i] = mat ? Whh[(gate * 128 + jj) * 128 + kk]
                 : Wih[(gate * 128 + jj) * 128 + kk];
  }
  if (i < 65536) { int c = i & 255, k = i >> 8;
    PW2[i] = (c < 128) ? Wl2[c * 256 + k] : Wr2[(c - 128) * 256 + k]; }
  if (i < 20480) { int g = i % 640, k = i / 640;
    PW1[i] = (g < 256) ? Wl1[g * 32 + k] : (g < 512) ? Wr1[(g - 256) * 32 + k]
                                                     : Wp[(g - 512) * 32 + k]; }
  if (i < 1024) { int u = i & 3, jj = (i >> 2) & 127, L = i >> 9;
    BC[i] = (L ? bih1 : bih0)[u * 128 + jj] + (L ? bhh1 : bhh0)[u * 128 + jj]; }
  if (i < 768) {
    if (i < 256) ABF[i] = g1[i] * rsqrtf(v1[i] + EPS_BN);
    else if (i < 512) { int c = i - 256; float a = g1[c] * rsqrtf(v1[c] + EPS_BN);
      ABF[i] = (bg1[c] - m1[c]) * a + be1[c]; }
    else if (i < 640) { int c = i - 512; ABF[i] = g2[c] * rsqrtf(v2[c] + EPS_BN); }
    else { int c = i - 640; float a = g2[c] * rsqrtf(v2[c] + EPS_BN);
      ABF[i] = (bg2[c] - m2[c]) * a + be2[c]; }
  }
  if (i < 13120) {
    if (i < 832) { int l = i & 63, c = i >> 6; HWT[i] = Ws1[l * 13 + c]; }
    else if (i < 2880) { int k = i - 832; int l = k & 31, jj = k >> 5; HWT[i] = Ws2[l * 64 + jj]; }
    else { int k = i - 2880; int l = k & 63, r = k >> 6; HWT[i] = Wh1[l * 160 + r]; }
  }
}

// ---------------- projection 1: x -> xl1(256) | xr1(256) | xp(128) ----------------
__global__ __launch_bounds__(320)
void proj1_kernel(const float* __restrict__ X, const float* __restrict__ PW1,
                  const float* __restrict__ bp,
                  float* __restrict__ XL1, float* __restrict__ XR1, float* __restrict__ XP)
{
  __shared__ __align__(16) float xs[32][16];
  const int tid = threadIdx.x;
  const int r0 = blockIdx.x * 16;
  for (int el = tid; el < 512; el += 320) {
    int r = el >> 5, k = el & 31;
    xs[k][r] = X[(size_t)(r0 + r) * 32 + k];
  }
  __syncthreads();
  const int gA = tid, gB = tid + 320;
  float accA[16], accB[16];
  const float iB = (gB >= 512) ? bp[gB - 512] : 0.f;
  #pragma unroll
  for (int r = 0; r < 16; ++r) { accA[r] = 0.f; accB[r] = iB; }
  for (int k = 0; k < 32; ++k) {
    float wA = PW1[k * 640 + gA], wB = PW1[k * 640 + gB];
    float xv[16];
    #pragma unroll
    for (int q = 0; q < 4; ++q)
      *reinterpret_cast<float4*>(&xv[q * 4]) = *reinterpret_cast<const float4*>(&xs[k][q * 4]);
    #pragma unroll
    for (int r = 0; r < 16; ++r) {
      accA[r] = fmaf(wA, xv[r], accA[r]);
      accB[r] = fmaf(wB, xv[r], accB[r]);
    }
  }
  for (int r = 0; r < 16; ++r) {
    size_t row = r0 + r;
    if (gA < 256) XL1[row * 256 + gA] = accA[r];
    else          XR1[row * 256 + (gA - 256)] = accA[r];
    if (gB < 512) XR1[row * 256 + (gB - 256)] = accB[r];
    else          XP[row * 128 + (gB - 512)] = accB[r];
  }
}

// ---------------- GAT layer 1 fused (2 heads, d=128) ----------------
__global__ __launch_bounds__(256)
void gat1_kernel(const float* __restrict__ XL, const float* __restrict__ XR,
                 const int* __restrict__ esrc,
                 const int* __restrict__ offs, const float* __restrict__ a1,
                 const float* __restrict__ ABF, float* __restrict__ H1)
{
  const int lane = threadIdx.x & 63;
  const int wv = threadIdx.x >> 6;
  const int n = blockIdx.x * 4 + wv;
  const int b = blockIdx.y;
  const int half = lane >> 5;
  __shared__ float lsh[4][128];
  const int beg = offs[n];
  const int deg = offs[n + 1] - beg;
  const float4 a4 = reinterpret_cast<const float4*>(a1)[lane];
  const float4* XLb = reinterpret_cast<const float4*>(XL) + (size_t)b * 64000;
  const float4 xr4 = reinterpret_cast<const float4*>(XR + (size_t)(b * 1000 + n) * 256)[lane];
  float m = -INFINITY, ssum = 0.f;
  {
    int sC = esrc[beg];
    float4 xc = XLb[(size_t)sC * 64 + lane];
    for (int i = 0; i < deg; ++i) {
      int nx = (i + 1 < deg) ? (i + 1) : i;
      int sN = esrc[beg + nx];
      float4 xn = XLb[(size_t)sN * 64 + lane];
      float p = lrelu(xc.x + xr4.x) * a4.x + lrelu(xc.y + xr4.y) * a4.y
              + lrelu(xc.z + xr4.z) * a4.z + lrelu(xc.w + xr4.w) * a4.w;
      p = rsum32(p);
      if (i < 64 && (lane & 31) == 0) lsh[wv][2 * i + half] = p;
      float mn = fmaxf(m, p);
      ssum = ssum * __expf(m - mn) + __expf(p - mn);
      m = mn;
      xc = xn;
    }
  }
  const float inv = 1.f / ssum;
  __builtin_amdgcn_wave_barrier();
  float4 acc = make_float4(0.f, 0.f, 0.f, 0.f);
  {
    int sC = esrc[beg];
    float4 xc = XLb[(size_t)sC * 64 + lane];
    for (int i = 0; i < deg; ++i) {
      int nx = (i + 1 < deg) ? (i + 1) : i;
      int sN = esrc[beg + nx];
      float4 xn = XLb[(size_t)sN * 64 + lane];
      float lg;
      if (i < 64) lg = lsh[wv][2 * i + half];
      else {
        float p = lrelu(xc.x + xr4.x) * a4.x + lrelu(xc.y + xr4.y) * a4.y
                + lrelu(xc.z + xr4.z) * a4.z + lrelu(xc.w + xr4.w) * a4.w;
        lg = rsum32(p);
      }
      const float al = __expf(lg - m) * inv;
      acc.x = fmaf(al, xc.x, acc.x);
      acc.y = fmaf(al, xc.y, acc.y);
      acc.z = fmaf(al, xc.z, acc.z);
      acc.w = fmaf(al, xc.w, acc.w);
      xc = xn;
    }
  }
  const float4 A4 = reinterpret_cast<const float4*>(ABF)[lane];
  const float4 B4 = reinterpret_cast<const float4*>(ABF + 256)[lane];
  float4 o;
  o.x = eluf(fmaf(acc.x, A4.x, B4.x));
  o.y = eluf(fmaf(acc.y, A4.y, B4.y));
  o.z = eluf(fmaf(acc.z, A4.z, B4.z));
  o.w = eluf(fmaf(acc.w, A4.w, B4.w));
  reinterpret_cast<float4*>(H1 + (size_t)(b * 1000 + n) * 256)[lane] = o;
}

// ---------------- projection 2: h1(256) -> xl2(128)|xr2(128) ----------------
__global__ __launch_bounds__(256)
void proj2_kernel(const float* __restrict__ H1, const float* __restrict__ PW2,
                  float* __restrict__ XL2, float* __restrict__ XR2)
{
  __shared__ __align__(16) float xs[256][20];
  const int tid = threadIdx.x;
  const int r0 = blockIdx.x * 16;
  for (int el = tid; el < 4096; el += 256) {
    int k = el & 255, r = el >> 8;
    xs[k][r] = H1[(size_t)(r0 + r) * 256 + k];
  }
  __syncthreads();
  float acc[16];
  #pragma unroll
  for (int r = 0; r < 16; ++r) acc[r] = 0.f;
  for (int k = 0; k < 256; ++k) {
    float wgt = PW2[k * 256 + tid];
    float xv[16];
    #pragma unroll
    for (int q = 0; q < 4; ++q)
      *reinterpret_cast<float4*>(&xv[q * 4]) = *reinterpret_cast<const float4*>(&xs[k][q * 4]);
    #pragma unroll
    for (int r = 0; r < 16; ++r) acc[r] = fmaf(wgt, xv[r], acc[r]);
  }
  float* dst = (tid < 128) ? XL2 : XR2;
  const int col = tid & 127;
  for (int r = 0; r < 16; ++r)
    dst[(size_t)(r0 + r) * 128 + col] = acc[r];
}

// ---------------- GAT layer 2 fused (1 head) + BN/ELU + residual ----------------
__global__ __launch_bounds__(256)
void gat2_kernel(const float* __restrict__ XL, const float* __restrict__ XR,
                 const int* __restrict__ esrc,
                 const int* __restrict__ offs, const float* __restrict__ a2,
                 const float* __restrict__ ABF, const float* __restrict__ XP,
                 float* __restrict__ Hout)
{
  const int lane = threadIdx.x & 63;
  const int wv = threadIdx.x >> 6;
  const int n = blockIdx.x * 4 + wv;
  const int b = blockIdx.y;
  __shared__ float lsh[4][96];
  const int beg = offs[n];
  const int deg = offs[n + 1] - beg;
  const float2 av = reinterpret_cast<const float2*>(a2)[lane];
  const float2* XLb = reinterpret_cast<const float2*>(XL) + (size_t)b * 64000;
  const float2 xr2 = reinterpret_cast<const float2*>(XR + (size_t)(b * 1000 + n) * 128)[lane];
  float m = -INFINITY, ssum = 0.f;
  {
    int sC = esrc[beg];
    float2 xc = XLb[(size_t)sC * 64 + lane];
    for (int i = 0; i < deg; ++i) {
      int nx = (i + 1 < deg) ? (i + 1) : i;
      int sN = esrc[beg + nx];
      float2 xn = XLb[(size_t)sN * 64 + lane];
      float p = lrelu(xc.x + xr2.x) * av.x + lrelu(xc.y + xr2.y) * av.y;
      p = rsum64(p);
      if (i < 96 && lane == 0) lsh[wv][i] = p;
      float mn = fmaxf(m, p);
      ssum = ssum * __expf(m - mn) + __expf(p - mn);
      m = mn;
      xc = xn;
    }
  }
  const float inv = 1.f / ssum;
  __builtin_amdgcn_wave_barrier();
  float2 acc = make_float2(0.f, 0.f);
  {
    int sC = esrc[beg];
    float2 xc = XLb[(size_t)sC * 64 + lane];
    for (int i = 0; i < deg; ++i) {
      int nx = (i + 1 < deg) ? (i + 1) : i;
      int sN = esrc[beg + nx];
      float2 xn = XLb[(size_t)sN * 64 + lane];
      float lg;
      if (i < 96) lg = lsh[wv][i];
      else {
        float p = lrelu(xc.x + xr2.x) * av.x + lrelu(xc.y + xr2.y) * av.y;
        lg = rsum64(p);
      }
      const float al = __expf(lg - m) * inv;
      acc.x = fmaf(al, xc.x, acc.x);
      acc.y = fmaf(al, xc.y, acc.y);
      xc = xn;
    }
  }
  const float2 A2 = reinterpret_cast<const float2*>(ABF + 512)[lane];
  const float2 B2 = reinterpret_cast<const float2*>(ABF + 640)[lane];
  const float2 xp = reinterpret_cast<const float2*>(XP + (size_t)(b * 1000 + n) * 128)[lane];
  float2 o;
  o.x = eluf(fmaf(acc.x, A2.x, B2.x)) + xp.x;
  o.y = eluf(fmaf(acc.y, A2.y, B2.y)) + xp.y;
  reinterpret_cast<float2*>(Hout + (size_t)(b * 1000 + n) * 128)[lane] = o;
}

// ---------------- fused 2-layer LSTM (8-way k-split, 2 units/thread) ----------------
#define FMA4(A, W, S) { (A).x = fmaf((W).x, (S), (A).x); (A).y = fmaf((W).y, (S), (A).y); \
                        (A).z = fmaf((W).z, (S), (A).z); (A).w = fmaf((W).w, (S), (A).w); }
#define AD4(a, b) { (a).x += (b).x; (a).y += (b).y; (a).z += (b).z; (a).w += (b).w; }
#define LROW 140

__device__ __forceinline__ float4 shflx4(float4 v, int msk) {
  float4 r;
  r.x = __shfl_xor(v.x, msk); r.y = __shfl_xor(v.y, msk);
  r.z = __shfl_xor(v.z, msk); r.w = __shfl_xor(v.w, msk);
  return r;
}

// Two j-units per thread: each x float4 read from LDS feeds 8 FMA4s
// (4 dk x 2 units), halving LDS traffic vs the 1-unit/thread version.
__device__ __forceinline__ void gates8x2(const float4* __restrict__ wbA,
                                         const float4* __restrict__ wbB,
                                         const float* XS, int xoff,
                                         float4 (&gA)[16], float4 (&gB)[16])
{
  #pragma unroll 2
  for (int q = 0; q < 8; ++q) {
    const float4* wqA = wbA + q * 256;
    const float4* wqB = wbB + q * 256;
    float4 a0 = wqA[0], a1 = wqA[64], a2 = wqA[128], a3 = wqA[192];
    float4 b0 = wqB[0], b1 = wqB[64], b2 = wqB[128], b3 = wqB[192];
    const float* xp = XS + xoff + (q << 2);
    #pragma unroll
    for (int s = 0; s < 16; ++s) {
      float4 xv = *reinterpret_cast<const float4*>(xp + s * LROW);
      FMA4(gA[s], a0, xv.x); FMA4(gA[s], a1, xv.y);
      FMA4(gA[s], a2, xv.z); FMA4(gA[s], a3, xv.w);
      FMA4(gB[s], b0, xv.x); FMA4(gB[s], b1, xv.y);
      FMA4(gB[s], b2, xv.z); FMA4(gB[s], b3, xv.w);
    }
  }
}

// narrowing 3-round butterfly over p = lane>>3; result: seqs 2p, 2p+1
__device__ __forceinline__ void reduce8(float4 (&g)[16], int lane, float4& ga, float4& gb)
{
  const bool b4 = (lane & 32) != 0, b2 = (lane & 16) != 0, b1 = (lane & 8) != 0;
  float4 t[8];
  #pragma unroll
  for (int i = 0; i < 8; ++i) {
    float4 keep = b4 ? g[8 + i] : g[i];
    float4 send = b4 ? g[i] : g[8 + i];
    float4 r = shflx4(send, 32);
    AD4(keep, r); t[i] = keep;
  }
  float4 u[4];
  #pragma unroll
  for (int i = 0; i < 4; ++i) {
    float4 keep = b2 ? t[4 + i] : t[i];
    float4 send = b2 ? t[i] : t[4 + i];
    float4 r = shflx4(send, 16);
    AD4(keep, r); u[i] = keep;
  }
  {
    float4 keep = b1 ? u[2] : u[0];
    float4 send = b1 ? u[0] : u[2];
    float4 r = shflx4(send, 8);
    AD4(keep, r); ga = keep;
  }
  {
    float4 keep = b1 ? u[3] : u[1];
    float4 send = b1 ? u[1] : u[3];
    float4 r = shflx4(send, 8);
    AD4(keep, r); gb = keep;
  }
}

__device__ __forceinline__ float cellf(float4 g, float& c) {
  const float ig = 1.f / (1.f + __expf(-g.x));
  const float fg = 1.f / (1.f + __expf(-g.y));
  const float gg = tanhf(g.z);
  const float og = 1.f / (1.f + __expf(-g.w));
  c = fmaf(fg, c, ig * gg);
  return og * tanhf(c);
}

// 512 threads = 8 waves; LDS padded to ~85 KB forces 1 WG/CU = 2 waves/EU,
// so the RA's occupancy-optimal VGPR budget is 256 (working set ~210: gA/gB
// 128 + weights 32 + states). The 1024-thread shape was hard-capped at 128
// and spilled ~2 GB; it was also LDS-bound (2 MB ds_read per layer-step).
__global__ __launch_bounds__(512)
__attribute__((amdgpu_waves_per_eu(2, 2)))
void lstm_kernel(const float* __restrict__ Hin, const float* __restrict__ PLW,
                 const float* __restrict__ BC, float* __restrict__ LO)
{
  __shared__ __align__(16) float xb[2][16][LROW];
  __shared__ __align__(16) float h1s[16][LROW];
  __shared__ __align__(16) float h2b[2][16][LROW];
  __shared__ float ldspad[10240];          // occupancy limiter: 40 KB
  const int tid = threadIdx.x;
  const int lane = tid & 63;
  const int w = tid >> 6;                  // 0..7
  const int jlo = lane & 7;
  const int p = lane >> 3;                 // 0..7: (k,mat) slice; mat = p>>2
  const int jA = (w << 3) + jlo;           // unit 0..63
  const int jB = jA + 64;                  // unit 64..127
  const int xoff = 36 * (p & 3);
  const bool hi = p >= 4;                  // hh side
  const int joA = jA + ((jA >> 5) << 2);
  const int joB = jB + ((jB >> 5) << 2);
  const int q0 = blockIdx.x << 4;
  const int s0 = 2 * p;                    // owned seqs after reduce
  if (blockIdx.x > 100000) { ldspad[tid] = BC[tid]; LO[tid] = ldspad[tid]; } // keep pad live
  for (int i = tid; i < 16 * LROW; i += 512) {
    (&h1s[0][0])[i] = 0.f;
    (&h2b[0][0][0])[i] = 0.f;
  }
  #pragma unroll
  for (int c = 0; c < 4; ++c) {
    int el = (c << 9) + tid;
    int s = el >> 7, k = el & 127;
    xb[0][s][k + ((k >> 5) << 2)] = Hin[((size_t)(((q0 + s) << 4))) * 128 + k];
  }
  const float4 b1A = *reinterpret_cast<const float4*>(BC + (jA << 2));
  const float4 b1B = *reinterpret_cast<const float4*>(BC + (jB << 2));
  const float4 b2A = *reinterpret_cast<const float4*>(BC + 512 + (jA << 2));
  const float4 b2B = *reinterpret_cast<const float4*>(BC + 512 + (jB << 2));
  const float4* PLW4 = reinterpret_cast<const float4*>(PLW);
  const float4* wbA1 = PLW4 + (w << 11) + lane;
  const float4* wbB1 = PLW4 + ((w + 8) << 11) + lane;
  const float4* wbA2 = wbA1 + 32768;
  const float4* wbB2 = wbB1 + 32768;
  float c1Aa = 0.f, c1Ab = 0.f, c1Ba = 0.f, c1Bb = 0.f;
  float c2Aa = 0.f, c2Ab = 0.f, c2Ba = 0.f, c2Bb = 0.f;
  __syncthreads();
  int cur = 0;
  for (int t = 0; t < 16; ++t) {
    if (t < 15) {
      #pragma unroll
      for (int c = 0; c < 4; ++c) {
        int el = (c << 9) + tid;
        int s = el >> 7, k = el & 127;
        xb[cur ^ 1][s][k + ((k >> 5) << 2)] =
            Hin[((size_t)(((q0 + s) << 4) + (t + 1))) * 128 + k];
      }
    }
    float4 gA[16], gB[16];
    #pragma unroll
    for (int s = 0; s < 16; ++s) {
      gA[s] = make_float4(0.f, 0.f, 0.f, 0.f);
      gB[s] = make_float4(0.f, 0.f, 0.f, 0.f);
    }
    gates8x2(wbA1, wbB1, hi ? &h1s[0][0] : &xb[cur][0][0], xoff, gA, gB);
    float4 gaA, gbA, gaB, gbB;
    reduce8(gA, lane, gaA, gbA);
    reduce8(gB, lane, gaB, gbB);
    AD4(gaA, b1A); AD4(gbA, b1A); AD4(gaB, b1B); AD4(gbB, b1B);
    float h1Aa = cellf(gaA, c1Aa), h1Ab = cellf(gbA, c1Ab);
    float h1Ba = cellf(gaB, c1Ba), h1Bb = cellf(gbB, c1Bb);
    __syncthreads();                       // (A) all gates-1 reads done
    h1s[s0][joA] = h1Aa;  h1s[s0 + 1][joA] = h1Ab;
    h1s[s0][joB] = h1Ba;  h1s[s0 + 1][joB] = h1Bb;
    __syncthreads();                       // (B) h1 visible
    #pragma unroll
    for (int s = 0; s < 16; ++s) {
      gA[s] = make_float4(0.f, 0.f, 0.f, 0.f);
      gB[s] = make_float4(0.f, 0.f, 0.f, 0.f);
    }
    gates8x2(wbA2, wbB2, hi ? &h2b[cur][0][0] : &h1s[0][0], xoff, gA, gB);
    reduce8(gA, lane, gaA, gbA);
    reduce8(gB, lane, gaB, gbB);
    AD4(gaA, b2A); AD4(gbA, b2A); AD4(gaB, b2B); AD4(gbB, b2B);
    float h2Aa = cellf(gaA, c2Aa), h2Ab = cellf(gbA, c2Ab);
    float h2Ba = cellf(gaB, c2Ba), h2Bb = cellf(gbB, c2Bb);
    h2b[cur ^ 1][s0][joA] = h2Aa;  h2b[cur ^ 1][s0 + 1][joA] = h2Ab;
    h2b[cur ^ 1][s0][joB] = h2Ba;  h2b[cur ^ 1][s0 + 1][joB] = h2Bb;
    LO[((size_t)(((q0 + s0) << 4) + t)) * 128 + jA] = h2Aa;
    LO[((size_t)(((q0 + s0 + 1) << 4) + t)) * 128 + jA] = h2Ab;
    LO[((size_t)(((q0 + s0) << 4) + t)) * 128 + jB] = h2Ba;
    LO[((size_t)(((q0 + s0 + 1) << 4) + t)) * 128 + jB] = h2Bb;
    cur ^= 1;
  }
}

// ---------------- attention pool + skip MLP + head ----------------
__global__ __launch_bounds__(64)
void attn_kernel(const float* __restrict__ LO, const float* __restrict__ X,
                 const float* __restrict__ Wa, const float* __restrict__ ba,
                 const float* __restrict__ bs1, const float* __restrict__ bs2,
                 const float* __restrict__ bh1, const float* __restrict__ bh2,
                 const float* __restrict__ Wh2, const float* __restrict__ HWT,
                 float* __restrict__ out)
{
  const int q = blockIdx.x, l = threadIdx.x;
  const float* lob = LO + (size_t)q * 2048;
  float loa[16], lobv[16];
  #pragma unroll
  for (int t = 0; t < 16; ++t) {
    loa[t]  = lob[t * 128 + l];
    lobv[t] = lob[t * 128 + 64 + l];
  }
  const float wa = Wa[l], wb = Wa[64 + l];
  float sc[16];
  #pragma unroll
  for (int t = 0; t < 16; ++t) sc[t] = rsum64(loa[t] * wa + lobv[t] * wb) + ba[0];
  float mx = sc[0];
  #pragma unroll
  for (int t = 1; t < 16; ++t) mx = fmaxf(mx, sc[t]);
  float den = 0.f;
  #pragma unroll
  for (int t = 0; t < 16; ++t) { sc[t] = __expf(sc[t] - mx); den += sc[t]; }
  const float inv = 1.f / den;
  float ca = 0.f, cb = 0.f;
  #pragma unroll
  for (int t = 0; t < 16; ++t) {
    float wgt = sc[t] * inv;
    ca = fmaf(wgt, loa[t], ca);
    cb = fmaf(wgt, lobv[t], cb);
  }
  __shared__ float zsh[160];
  __shared__ float hsk[64];
  __shared__ float skin[16];
  zsh[l] = ca; zsh[64 + l] = cb;
  const int bb = q / 1000, nn = q - bb * 1000;
  if (l < 13) skin[l] = X[(size_t)((bb * 16 + 15) * 1000 + nn) * 32 + l];
  __syncthreads();
  float h1 = bs1[l];
  for (int c = 0; c < 13; ++c) h1 = fmaf(skin[c], HWT[c * 64 + l], h1);
  h1 = geluf(h1);
  hsk[l] = h1;
  __syncthreads();
  if (l < 32) {
    float a = bs2[l];
    for (int jj = 0; jj < 64; ++jj) a = fmaf(hsk[jj], HWT[832 + jj * 32 + l], a);
    zsh[128 + l] = a;
  }
  __syncthreads();
  float hh = bh1[l];
  for (int r = 0; r < 160; ++r) hh = fmaf(zsh[r], HWT[2880 + r * 64 + l], hh);
  hh = geluf(hh);
  float s = rsum64(hh * Wh2[l]);
  if (l == 0) out[q] = s + bh2[0];
}

// ---------------- launch ----------------
extern "C" void kernel_launch(void* const* d_in, const int* in_sizes, int n_in,
                              void* d_out, int out_size, void* d_ws, size_t ws_size,
                              hipStream_t stream)
{
  const float* x    = (const float*)d_in[0];
  const int*   ei   = (const int*)d_in[1];
  const float* Wp   = (const float*)d_in[2];
  const float* bp   = (const float*)d_in[3];
  const float* Wl1  = (const float*)d_in[4];
  const float* Wr1  = (const float*)d_in[5];
  const float* a1   = (const float*)d_in[6];
  const float* bg1  = (const float*)d_in[7];
  const float* g1   = (const float*)d_in[8];
  const float* be1  = (const float*)d_in[9];
  const float* m1   = (const float*)d_in[10];
  const float* v1   = (const float*)d_in[11];
  const float* Wl2  = (const float*)d_in[12];
  const float* Wr2  = (const float*)d_in[13];
  const float* a2   = (const float*)d_in[14];
  const float* bg2  = (const float*)d_in[15];
  const float* g2   = (const float*)d_in[16];
  const float* be2  = (const float*)d_in[17];
  const float* m2   = (const float*)d_in[18];
  const float* v2   = (const float*)d_in[19];
  const float* Wih0 = (const float*)d_in[20];
  const float* Whh0 = (const float*)d_in[21];
  const float* bih0 = (const float*)d_in[22];
  const float* bhh0 = (const float*)d_in[23];
  const float* Wih1 = (const float*)d_in[24];
  const float* Whh1 = (const float*)d_in[25];
  const float* bih1 = (const float*)d_in[26];
  const float* bhh1 = (const float*)d_in[27];
  const float* Wa   = (const float*)d_in[28];
  const float* ba   = (const float*)d_in[29];
  const float* Ws1  = (const float*)d_in[30];
  const float* bs1  = (const float*)d_in[31];
  const float* Ws2  = (const float*)d_in[32];
  const float* bs2  = (const float*)d_in[33];
  const float* Wh1  = (const float*)d_in[34];
  const float* bh1  = (const float*)d_in[35];
  const float* Wh2  = (const float*)d_in[36];
  const float* bh2  = (const float*)d_in[37];

  float* ws = (float*)d_ws;
  int* srcD   = (int*)(ws + O_SRCD);
  int* dstD   = (int*)(ws + O_DSTD);
  int* counts = (int*)(ws + O_COUNTS);
  int* offs   = (int*)(ws + O_OFFS);
  int* curs   = (int*)(ws + O_CURS);
  int* esrc   = (int*)(ws + O_EIDX);
  float* PW1  = ws + O_PW1;
  float* PW2  = ws + O_PW2;
  float* PLW  = ws + O_LW;
  float* BC   = ws + O_BCOMB;
  float* ABF  = ws + O_ABF;
  float* HWT  = ws + O_HWT;
  float* XL1  = ws + O_BIG0;
  float* XR1  = ws + O_BIG1;
  float* H1   = ws + O_BIG2;
  float* XP   = ws + O_BIG3;
  float* Hres = ws + O_BIG4;
  float* XL2  = ws + O_BIG0;             // reuse (XL1 dead)
  float* XR2  = ws + O_BIG0 + 8192000u;
  float* LOp  = ws + O_BIG1;             // reuse (XR1 dead)
  float* outp = (float*)d_out;

  prep_edges<<<67, 256, 0, stream>>>(ei, srcD, dstD, counts);
  hist_kernel<<<67, 256, 0, stream>>>(dstD, counts);
  scan_kernel<<<1, 1024, 0, stream>>>(counts, offs, curs);
  fill_kernel<<<67, 256, 0, stream>>>(srcD, dstD, curs, esrc);
  pack_kernel<<<1024, 256, 0, stream>>>(Wl1, Wr1, Wp, Wl2, Wr2,
      Wih0, Whh0, bih0, bhh0, Wih1, Whh1, bih1, bhh1,
      g1, be1, m1, v1, bg1, g2, be2, m2, v2, bg2,
      Ws1, Ws2, Wh1, PW1, PW2, PLW, BC, ABF, HWT);
  proj1_kernel<<<4000, 320, 0, stream>>>(x, PW1, bp, XL1, XR1, XP);
  gat1_kernel<<<dim3(250, 64), 256, 0, stream>>>(XL1, XR1, esrc, offs, a1, ABF, H1);
  proj2_kernel<<<4000, 256, 0, stream>>>(H1, PW2, XL2, XR2);
  gat2_kernel<<<dim3(250, 64), 256, 0, stream>>>(XL2, XR2, esrc, offs, a2, ABF, XP, Hres);
  lstm_kernel<<<250, 512, 0, stream>>>(Hres, PLW, BC, LOp);
  attn_kernel<<<4000, 64, 0, stream>>>(LOp, x, Wa, ba, bs1, bs2, bh1, bh2, Wh2, HWT, outp);
}